// Round 6
// baseline (1196.948 us; speedup 1.0000x reference)
//
#include <hip/hip_runtime.h>
#include <math.h>

typedef __bf16 bf16x8 __attribute__((ext_vector_type(8)));
typedef float f32x4 __attribute__((ext_vector_type(4)));
typedef unsigned short u16;
typedef u16 u16x8 __attribute__((ext_vector_type(8)));

#define DI __device__ __forceinline__

DI u16 f2bf(float f) {
  union { float f; unsigned u; } v; v.f = f;
  unsigned r = v.u + 0x7FFFu + ((v.u >> 16) & 1u);  // RNE
  return (u16)(r >> 16);
}

DI void gload_lds16(const u16* g, u16* l) {
  // dest = wave-uniform base + lane*16B (HW semantics); src is per-lane.
  __builtin_amdgcn_global_load_lds(
      (const __attribute__((address_space(1))) unsigned int*)g,
      (__attribute__((address_space(3))) unsigned int*)l, 16, 0, 0);
}

// ---------------- mean-pool embeddings -> sentM [192][512] bf16 ---------
__global__ __launch_bounds__(256) void meanpool_k(const int* __restrict__ x,
    const float* __restrict__ emb, u16* __restrict__ sentM) {
  int bs = blockIdx.x; int s = bs >> 6, b = bs & 63;
  int t = threadIdx.x;
  float a0 = 0.f, a1 = 0.f;
  for (int lt = 0; lt < 32; ++lt) {
    int tok = x[b * 128 + s * 32 + lt];
    const float* e = emb + (long)tok * 512;
    a0 += e[t]; a1 += e[t + 256];
  }
  sentM[(long)bs * 512 + t] = f2bf(a0 * (1.f / 32.f));
  sentM[(long)bs * 512 + t + 256] = f2bf(a1 * (1.f / 32.f));
}

// ------- transpose + cvt, 64-wide output rows (full 128B bf16 lines) ----
// out[c*ostride + r] = bf16(in[r*C + c]); tile 64 r x 32 c; XOR-swizzled LDS.
DI void transpose64_body(const float* __restrict__ in, u16* __restrict__ out,
                         int C, int ostride) {
  __shared__ float tile[32 * 65];
  int c0 = blockIdx.x * 32, r0 = blockIdx.y * 64;
  int t = threadIdx.x;
  int cc = t & 31, rr0 = t >> 5;
#pragma unroll
  for (int i = 0; i < 8; ++i) {
    int rr = rr0 + 8 * i;
    tile[cc * 65 + (rr ^ ((cc & 7) << 3))] = in[(long)(r0 + rr) * C + c0 + cc];
  }
  __syncthreads();
  int cj = t >> 3, rj = t & 7;
  u16x8 v;
#pragma unroll
  for (int k = 0; k < 8; ++k)
    v[k] = f2bf(tile[cj * 65 + ((rj * 8 + k) ^ ((cj & 7) << 3))]);
  *(u16x8*)(out + (long)(c0 + cj) * ostride + r0 + rj * 8) = v;
}

__global__ __launch_bounds__(256) void transpose64(
    const float* __restrict__ in, u16* __restrict__ out, int R, int C,
    int ostride) {
  in += (long)blockIdx.z * (long)R * C;
  out += (long)blockIdx.z * (long)C * ostride;
  transpose64_body(in, out, C, ostride);
}

struct TJob { const float* in; u16* out; int R; int ostride; };
struct TJobs { TJob j[6]; };
__global__ __launch_bounds__(256) void transpose64_multi(TJobs jobs) {
  TJob jb = jobs.j[blockIdx.z];                 // all jobs C = 1024
  if ((int)(blockIdx.y * 64) >= jb.R) return;
  transpose64_body(jb.in, jb.out, 1024, jb.ostride);
}

// ---------------- small MFMA GEMM: out = tanh(A0|A1 @ B^T), N=1024 ------
// Depth-2 pipelined (3 LDS buffers, counted vmcnt), raw barriers.
__global__ __launch_bounds__(256) void gemm_small(
    const u16* __restrict__ A0, const u16* __restrict__ A1,
    const u16* __restrict__ Bt, u16* __restrict__ outp,
    int M, int K, int kSplit, int Astride, int Bstride) {
  int mt = blockIdx.x, ntb = blockIdx.y;
  __shared__ __align__(16) u16 As[3][2048];   // [kg0..3][row0..63] x 8 u16
  __shared__ __align__(16) u16 Bs[3][4096];   // [kg0..3][col0..127] x 8 u16
  const int t = threadIdx.x;
  const int w = t >> 6, l = t & 63, lr = l & 15, lg = l >> 4;
  int ar = mt * 64 + (t & 63); if (ar >= M) ar = M - 1;
  const u16* pB = Bt + (long)(ntb * 128 + (t & 127)) * Bstride + (t >> 7) * 8;
  const int ntk = K >> 5;

  auto STG = [&](int buf, int kt) {
    int k0 = kt << 5;
    const u16* srcA = (k0 < kSplit)
        ? A0 + (long)ar * Astride + k0 + w * 8
        : A1 + (long)ar * 1024 + (k0 - kSplit) + w * 8;
    gload_lds16(srcA, &As[buf][w * 512]);
    gload_lds16(pB + k0, &Bs[buf][w * 512]);
    gload_lds16(pB + k0 + 16, &Bs[buf][2048 + w * 512]);
  };
  STG(0, 0);
  if (ntk > 1) STG(1, 1);

  f32x4 acc[4][2] = {};
  for (int kt = 0; kt < ntk; ++kt) {
    int cb = kt % 3;
    if (kt + 2 < ntk) {
      STG((kt + 2) % 3, kt + 2);
      asm volatile("s_waitcnt vmcnt(6)" ::: "memory");
    } else if (kt + 1 < ntk) {
      asm volatile("s_waitcnt vmcnt(3)" ::: "memory");
    } else {
      asm volatile("s_waitcnt vmcnt(0)" ::: "memory");
    }
    __builtin_amdgcn_s_barrier();
    __builtin_amdgcn_sched_barrier(0);
    bf16x8 a[4], b[2];
#pragma unroll
    for (int mf = 0; mf < 4; ++mf)
      a[mf] = *(const bf16x8*)(&As[cb][(lg * 64 + mf * 16 + lr) * 8]);
#pragma unroll
    for (int nf = 0; nf < 2; ++nf)
      b[nf] = *(const bf16x8*)(&Bs[cb][(lg * 128 + w * 32 + nf * 16 + lr) * 8]);
#pragma unroll
    for (int mf = 0; mf < 4; ++mf)
#pragma unroll
      for (int nf = 0; nf < 2; ++nf)
        acc[mf][nf] = __builtin_amdgcn_mfma_f32_16x16x32_bf16(a[mf], b[nf], acc[mf][nf], 0, 0, 0);
    __builtin_amdgcn_s_barrier();
    __builtin_amdgcn_sched_barrier(0);
  }
#pragma unroll
  for (int mf = 0; mf < 4; ++mf)
#pragma unroll
    for (int j = 0; j < 4; ++j) {
      int r = mt * 64 + mf * 16 + lg * 4 + j;
      if (r < M) {
        u16* o = outp + (long)r * 1024 + ntb * 128 + w * 32;
#pragma unroll
        for (int nf = 0; nf < 2; ++nf)
          o[nf * 16 + lr] = f2bf(tanhf(acc[mf][nf][j]));
      }
    }
}

// ---------------- mid GEMM (128x128, BK=32) for ctx / cur ----------------
template <int MODE>
__global__ __launch_bounds__(256) void gemm_bf16(
    const u16* __restrict__ A, const u16* __restrict__ Bt,
    const float* __restrict__ Ww, const int* __restrict__ xtok,
    void* __restrict__ outp, int M) {
  int mt = blockIdx.x, nt = blockIdx.y, mz = blockIdx.z;
  if constexpr (MODE == 0) Bt += (long)mz << 20;  // U slice [1024][1024]

  __shared__ __align__(16) u16 As[128 * 32];
  __shared__ __align__(16) u16 Bs[128 * 32];

  const int t = threadIdx.x;
  const int w = t >> 6, l = t & 63;
  const int lr = l & 15, lg = l >> 4;
  const int wr = w >> 1, wc = w & 1;

  int ar0 = mt * 128 + (t >> 2);
  int ar1 = ar0 + 64;
  if (ar0 >= M) ar0 = 0;
  if (ar1 >= M) ar1 = 0;
  long arow0, arow1;
  if constexpr (MODE == 1) {
    arow0 = (long)(ar0 / 31) * 32 + (ar0 % 31) + 1;
    arow1 = (long)(ar1 / 31) * 32 + (ar1 % 31) + 1;
  } else {
    arow0 = ar0; arow1 = ar1;
  }

  const u16* ga0 = A + arow0 * 1024 + (t & 3) * 8;
  const u16* ga1 = A + arow1 * 1024 + (t & 3) * 8;
  const u16* gb0 = Bt + ((long)nt * 128 + (t >> 2)) * 1024 + (t & 3) * 8;
  const u16* gb1 = gb0 + 64 * 1024;

  u16* dA0 = As + w * 512; u16* dA1 = As + 2048 + w * 512;
  u16* dB0 = Bs + w * 512; u16* dB1 = Bs + 2048 + w * 512;

  f32x4 acc[4][4] = {};

  for (int kt = 0; kt < 32; ++kt) {
    __syncthreads();
    gload_lds16(ga0, dA0); gload_lds16(ga1, dA1);
    gload_lds16(gb0, dB0); gload_lds16(gb1, dB1);
    ga0 += 32; ga1 += 32; gb0 += 32; gb1 += 32;
    __syncthreads();
    bf16x8 a[4], b[4];
#pragma unroll
    for (int m = 0; m < 4; ++m)
      a[m] = *(const bf16x8*)&As[(wr * 64 + m * 16 + lr) * 32 + lg * 8];
#pragma unroll
    for (int n = 0; n < 4; ++n)
      b[n] = *(const bf16x8*)&Bs[(wc * 64 + n * 16 + lr) * 32 + lg * 8];
#pragma unroll
    for (int m = 0; m < 4; ++m)
#pragma unroll
      for (int n = 0; n < 4; ++n)
        acc[m][n] = __builtin_amdgcn_mfma_f32_16x16x32_bf16(a[m], b[n], acc[m][n], 0, 0, 0);
  }

#pragma unroll
  for (int m = 0; m < 4; ++m) {
#pragma unroll
    for (int j = 0; j < 4; ++j) {
      int r = mt * 128 + wr * 64 + m * 16 + lg * 4 + j;
      if (r >= M) continue;
      if constexpr (MODE == 0) {
        u16* oc = (u16*)outp;
#pragma unroll
        for (int n = 0; n < 4; ++n) {
          int col = nt * 128 + wc * 64 + n * 16 + lr;
          oc[((long)r * 32 + mz) * 1024 + col] = f2bf(tanhf(acc[m][n][j]));
        }
      } else {
        int sb = r / 31, l1 = r % 31;
        int s = sb >> 6, b = sb & 63;
        int widx = xtok[b * 128 + (s + 1) * 32 + l1];
        const float* wwr = Ww + (long)widx * 1024;
        u16* oc = (u16*)outp;
#pragma unroll
        for (int n = 0; n < 4; ++n) {
          int col = nt * 128 + wc * 64 + n * 16 + lr;
          oc[(long)r * 1024 + col] = f2bf(tanhf(acc[m][n][j] + wwr[col]));
        }
      }
    }
  }
}

// ---------------- BIG GEMM: 256x256, BK=64, 8-phase + read-ahead --------
// Fragments are read 1-2 phases before their MFMA (fixed banks a0/a1/b0/b1),
// so every lgkmcnt is pre-drained. Gray quadrant order (0,0)(0,1)(1,1)(1,0).
// vmcnt ledger: entry-of-group = 6 outstanding (A0,B0,B1 of next tile);
// VM10@p3/p7 retires A0(next), VM6@p4/p8 retires B0,B1,A1(next).
#define NONE ((void)0)
#define LGK12 asm volatile("s_waitcnt lgkmcnt(12)" ::: "memory")
#define LGK8  asm volatile("s_waitcnt lgkmcnt(8)" ::: "memory")
#define LGK0  asm volatile("s_waitcnt lgkmcnt(0)" ::: "memory")
#define VM10  asm volatile("s_waitcnt vmcnt(10)" ::: "memory")
#define VM6   asm volatile("s_waitcnt vmcnt(6)" ::: "memory")
#define VM0   asm volatile("s_waitcnt vmcnt(0)" ::: "memory")

#define STAGE_A(H, KT) do {                                                \
    const u16* _s = ((H) ? pA1 : pA0) + (KT) * 64;                         \
    u16* _d = lds + ((KT) & 1) * 16384 + (H) * 8192 + w * 512;             \
    gload_lds16(_s, _d); gload_lds16(_s + 32, _d + 4096);                  \
  } while (0)
#define STAGE_B(H, KT) do {                                                \
    const u16* _s = ((H) ? pB1 : pB0) + (KT) * 64;                         \
    u16* _d = lds + 32768 + ((KT) & 1) * 16384 + (H) * 8192 + w * 512;     \
    gload_lds16(_s, _d); gload_lds16(_s + 32, _d + 4096);                  \
  } while (0)

#define RD_A(bank, AB, MH) do {                                            \
    _Pragma("unroll") for (int ks = 0; ks < 2; ++ks)                       \
    _Pragma("unroll") for (int mf = 0; mf < 4; ++mf)                       \
      bank[mf][ks] = *(const bf16x8*)(lds + (AB) + (MH) * 8192 + laneA +   \
                                      ks * 4096 + mf * 128);               \
  } while (0)
#define RD_B(AB, NH) do {                                                  \
    _Pragma("unroll") for (int ks = 0; ks < 2; ++ks)                       \
    _Pragma("unroll") for (int nf = 0; nf < 2; ++nf)                       \
      b[NH][nf][ks] = *(const bf16x8*)(lds + 32768 + (AB) + (NH) * 8192 +  \
                                       laneB + ks * 4096 + nf * 128);      \
  } while (0)
#define POSTA(AB) RD_A(a0, AB, 0)
#define POST8(AB) do { RD_B(AB, 0); RD_B(AB, 1); RD_A(a1, AB, 1); } while (0)

#define MM(MH, NH) do {                                                    \
    _Pragma("unroll") for (int ks = 0; ks < 2; ++ks)                       \
    _Pragma("unroll") for (int mf = 0; mf < 4; ++mf)                       \
    _Pragma("unroll") for (int nf = 0; nf < 2; ++nf)                       \
      acc[(MH) * 4 + mf][(NH) * 2 + nf] =                                  \
          __builtin_amdgcn_mfma_f32_16x16x32_bf16(                         \
              (MH) ? a1[mf][ks] : a0[mf][ks], b[NH][nf][ks],               \
              acc[(MH) * 4 + mf][(NH) * 2 + nf], 0, 0, 0);                 \
  } while (0)

#define PH(MH, NH, LGW, STG, VMW, POST) do {                               \
    STG;                                                                   \
    __builtin_amdgcn_s_barrier();                                          \
    LGW;                                                                   \
    __builtin_amdgcn_sched_barrier(0);                                     \
    __builtin_amdgcn_s_setprio(1);                                         \
    MM(MH, NH);                                                            \
    __builtin_amdgcn_s_setprio(0);                                         \
    VMW;                                                                   \
    POST;                                                                  \
    __builtin_amdgcn_s_barrier();                                          \
  } while (0)

__global__ __launch_bounds__(512, 2) void gemm_big(
    const u16* __restrict__ A, const u16* __restrict__ Bt,
    const int* __restrict__ x, float* __restrict__ out) {
  // XCD k owns mt {3k,3k+1,3k+2}: A-slab (1.5 MB) stays L2-resident.
  int bid = blockIdx.x;                       // 3000 = 8 * 375
  int xcd = bid & 7, idx = bid >> 3;
  int nt = idx / 3;                           // 0..124
  int mt = xcd * 3 + idx % 3;                 // 0..23

  __shared__ __align__(16) u16 lds[65536];    // A [0,32768) | B [32768,65536)

  const int t = threadIdx.x;
  const int w = t >> 6, l = t & 63;
  const int lr = l & 15, lg = l >> 4;
  const int wm = w >> 2, wn = w & 3;          // 2 x 4 waves
  const int laneA = (lg * 128 + wm * 64 + lr) * 8;
  const int laneB = (lg * 128 + wn * 32 + lr) * 8;

  int arow0 = mt * 256 + (t & 127);
  int arow1 = arow0 + 128;
  if (arow0 > 5951) arow0 = 5951;
  if (arow1 > 5951) arow1 = 5951;
  const u16* pA0 = A + (long)arow0 * 1024 + (t >> 7) * 8;
  const u16* pA1 = A + (long)arow1 * 1024 + (t >> 7) * 8;
  const u16* pB0 = Bt + ((long)nt * 256 + (t & 127)) * 1024 + (t >> 7) * 8;
  const u16* pB1 = pB0 + 128 * 1024;

  f32x4 acc[8][4] = {};
  bf16x8 a0[4][2], a1[4][2], b[2][2][2];

  // prologue: 7 half-tiles staged; retire tile 0; pre-read tile-0 frags
  STAGE_A(0, 0); STAGE_B(0, 0); STAGE_B(1, 0); STAGE_A(1, 0);
  STAGE_A(0, 1); STAGE_B(0, 1); STAGE_B(1, 1);
  VM6;
  __builtin_amdgcn_s_barrier();
  POSTA(0);        // a0: 8 reads
  RD_B(0, 0);      // b0: 4
  RD_B(0, 1);      // b1: 4
  RD_A(a1, 0, 1);  // a1: 8

  for (int g = 0; g < 14; g += 2) {
    PH(0, 0, LGK12, STAGE_A(1, g + 1), NONE, NONE);
    PH(0, 1, LGK8,  STAGE_A(0, g + 2), NONE, NONE);
    PH(1, 1, LGK0,  STAGE_B(0, g + 2), VM10, POSTA(16384));
    PH(1, 0, LGK8,  STAGE_B(1, g + 2), VM6,  POST8(16384));
    PH(0, 0, LGK12, STAGE_A(1, g + 2), NONE, NONE);
    PH(0, 1, LGK8,  STAGE_A(0, g + 3), NONE, NONE);
    PH(1, 1, LGK0,  STAGE_B(0, g + 3), VM10, POSTA(0));
    PH(1, 0, LGK8,  STAGE_B(1, g + 3), VM6,  POST8(0));
  }
  // tail group: tiles 14,15 (only A1(15) left to stage)
  PH(0, 0, LGK12, STAGE_A(1, 15), NONE, NONE);
  PH(0, 1, LGK8,  NONE, NONE, NONE);
  PH(1, 1, LGK0,  NONE, VM6,  POSTA(16384));
  PH(1, 0, LGK8,  NONE, VM0,  POST8(16384));
  PH(0, 0, LGK12, NONE, NONE, NONE);
  PH(0, 1, LGK8,  NONE, NONE, NONE);
  PH(1, 1, LGK0,  NONE, NONE, NONE);
  PH(1, 0, LGK8,  NONE, NONE, NONE);

  // epilogue: per-wave LDS transpose -> full 128B-line nontemporal dwordx4.
  // Pad rows 5952..6143 emit the one-hot l=0 rows (all d_out covered here).
  float* T = (float*)lds + w * 2112;
#pragma unroll
  for (int mh = 0; mh < 2; ++mh)
#pragma unroll
    for (int nh = 0; nh < 2; ++nh) {
#pragma unroll
      for (int mf = 0; mf < 4; ++mf)
#pragma unroll
        for (int j = 0; j < 4; ++j)
#pragma unroll
          for (int nf = 0; nf < 2; ++nf)
            T[(mf * 16 + lg * 4 + j) * 33 + nf * 16 + lr] =
                acc[mh * 4 + mf][nh * 2 + nf][j];
#pragma unroll
      for (int i = 0; i < 8; ++i) {
        int row = (l >> 3) + 8 * i;
        int c4 = (l & 7) * 4;
        f32x4 v;
        v[0] = T[row * 33 + c4];     v[1] = T[row * 33 + c4 + 1];
        v[2] = T[row * 33 + c4 + 2]; v[3] = T[row * 33 + c4 + 3];
        int r = mt * 256 + mh * 128 + wm * 64 + row;
        int colb = nt * 256 + nh * 128 + wn * 32 + c4;
        float* o;
        if (r < 5952) {
          int s = r / 1984, rem = r % 1984;
          int bb = rem / 31, l1 = rem % 31;
          o = out + ((long)bb * 96 + s * 32 + l1 + 1) * 32000 + colb;
        } else {
          int i2 = r - 5952;
          int s = i2 >> 6, bb = i2 & 63;
          int tok = x[bb * 128 + (s + 1) * 32];
          v[0] = (colb == tok);     v[1] = (colb + 1 == tok);
          v[2] = (colb + 2 == tok); v[3] = (colb + 3 == tok);
          o = out + ((long)bb * 96 + s * 32) * 32000 + colb;
        }
        __builtin_nontemporal_store(v, (f32x4*)o);
      }
    }
}

// ------------------------------- launch ---------------------------------
extern "C" void kernel_launch(void* const* d_in, const int* in_sizes, int n_in,
                              void* d_out, int out_size, void* d_ws, size_t ws_size,
                              hipStream_t stream) {
  const int*   x    = (const int*)d_in[0];
  const float* emb  = (const float*)d_in[2];
  const float* Wcsm = (const float*)d_in[3];
  const float* Wx1  = (const float*)d_in[4];
  const float* Wh1  = (const float*)d_in[5];
  const float* Wx2  = (const float*)d_in[6];
  const float* Wh2  = (const float*)d_in[7];
  const float* U    = (const float*)d_in[8];
  const float* Ww   = (const float*)d_in[9];
  const float* Wc   = (const float*)d_in[10];
  const float* Wfc  = (const float*)d_in[11];
  float* out = (float*)d_out;

  char* ws = (char*)d_ws;
  u16* sentM = (u16*)(ws + 0);          //  196608 [192][512]
  u16* sentH = (u16*)(ws + 196608);     //  393216 [192][1024]
  u16* h1a   = (u16*)(ws + 589824);     //  131072 [64][1024]
  u16* h1b   = (u16*)(ws + 720896);     //  131072
  u16* hsb   = (u16*)(ws + 851968);     //  393216 [192][1024]
  u16* ctx   = (u16*)(ws + 1245184);    // 12582912 [192*32][1024]
  u16* WcsmT = (u16*)(ws + 1245184);    //  1048576 [1024][512]   (pre-ctx)
  u16* WxhT1 = (u16*)(ws + 2293760);    //  4194304 [1024][2048]  (pre-ctx)
  u16* WxhT2 = (u16*)(ws + 6488064);    //  4194304 [1024][2048]  (pre-ctx)
  u16* cur   = (u16*)(ws + 13828096);   // 12189696 [5952][1024]
  u16* WcT   = (u16*)(ws + 26017792);   //  2097152 [1024][1024]
  u16* BIG   = (u16*)(ws + 28114944);   // 67108864 U^T then Wfc^T

  // all six [1024][1024/512] weight transposes in one launch
  TJobs jobs;
  jobs.j[0] = {Wx1,  WxhT1,        1024, 2048};
  jobs.j[1] = {Wh1,  WxhT1 + 1024, 1024, 2048};
  jobs.j[2] = {Wx2,  WxhT2,        1024, 2048};
  jobs.j[3] = {Wh2,  WxhT2 + 1024, 1024, 2048};
  jobs.j[4] = {Wc,   WcT,          1024, 1024};
  jobs.j[5] = {Wcsm, WcsmT,         512,  512};
  transpose64_multi<<<dim3(32, 16, 6), 256, 0, stream>>>(jobs);

  // CSM: mean-pool + tanh(sentM @ Wcsm)
  meanpool_k<<<192, 256, 0, stream>>>(x, emb, sentM);
  gemm_small<<<dim3(3, 8), 256, 0, stream>>>(sentM, sentM, WcsmT, sentH, 192, 512, 512, 512, 512);

  // RNN: h = tanh([x h] @ [Wx;Wh]) via concat-K; hs[s] lands in hsb rows s*64..
  gemm_small<<<dim3(1, 8), 256, 0, stream>>>(sentH,          h1a, WxhT1, h1a,           64, 1024, 1024, 1024, 2048);
  gemm_small<<<dim3(1, 8), 256, 0, stream>>>(h1a,            h1a, WxhT2, hsb,           64, 1024, 1024, 1024, 2048);
  gemm_small<<<dim3(1, 8), 256, 0, stream>>>(sentH + 65536,  h1a, WxhT1, h1b,           64, 2048, 1024, 1024, 2048);
  gemm_small<<<dim3(1, 8), 256, 0, stream>>>(h1b,            hsb, WxhT2, hsb + 65536,   64, 2048, 1024, 1024, 2048);
  gemm_small<<<dim3(1, 8), 256, 0, stream>>>(sentH + 131072, h1b, WxhT1, h1a,           64, 2048, 1024, 1024, 2048);
  gemm_small<<<dim3(1, 8), 256, 0, stream>>>(h1a, hsb + 65536, WxhT2, hsb + 131072,     64, 2048, 1024, 1024, 2048);

  // contexts: per-m GEMM against U[m]^T
  transpose64<<<dim3(32, 16, 32), 256, 0, stream>>>(U, BIG, 1024, 1024, 1024);
  gemm_bf16<0><<<dim3(2, 8, 32), 256, 0, stream>>>(hsb, BIG, nullptr, nullptr, (void*)ctx, 192);

  // cur: GEMM against Wc^T with Ww gather + tanh epilogue
  gemm_bf16<1><<<dim3(47, 8, 1), 256, 0, stream>>>(ctx, WcT, Ww, x, (void*)cur, 5952);

  // y_sec: read-ahead 8-phase 256^2 GEMM vs Wfc^T; writes ALL of d_out
  transpose64<<<dim3(1000, 16, 1), 256, 0, stream>>>(Wfc, BIG, 1024, 32000, 1024);
  gemm_big<<<3000, 512, 0, stream>>>(cur, BIG, x, out);
}

// Round 8
// 1170.535 us; speedup vs baseline: 1.0226x; 1.0226x over previous
//
#include <hip/hip_runtime.h>
#include <math.h>

typedef __bf16 bf16x8 __attribute__((ext_vector_type(8)));
typedef float f32x4 __attribute__((ext_vector_type(4)));
typedef unsigned short u16;
typedef u16 u16x8 __attribute__((ext_vector_type(8)));

#define DI __device__ __forceinline__

DI u16 f2bf(float f) {
  union { float f; unsigned u; } v; v.f = f;
  unsigned r = v.u + 0x7FFFu + ((v.u >> 16) & 1u);  // RNE
  return (u16)(r >> 16);
}

DI void gload_lds16(const u16* g, u16* l) {
  // dest = wave-uniform base + lane*16B (HW semantics); src is per-lane.
  __builtin_amdgcn_global_load_lds(
      (const __attribute__((address_space(1))) unsigned int*)g,
      (__attribute__((address_space(3))) unsigned int*)l, 16, 0, 0);
}

// ---------------- mean-pool embeddings -> sentM [192][512] bf16 ---------
__global__ __launch_bounds__(256) void meanpool_k(const int* __restrict__ x,
    const float* __restrict__ emb, u16* __restrict__ sentM) {
  int bs = blockIdx.x; int s = bs >> 6, b = bs & 63;
  int t = threadIdx.x;
  float a0 = 0.f, a1 = 0.f;
  for (int lt = 0; lt < 32; ++lt) {
    int tok = x[b * 128 + s * 32 + lt];
    const float* e = emb + (long)tok * 512;
    a0 += e[t]; a1 += e[t + 256];
  }
  sentM[(long)bs * 512 + t] = f2bf(a0 * (1.f / 32.f));
  sentM[(long)bs * 512 + t + 256] = f2bf(a1 * (1.f / 32.f));
}

// ------- transpose + cvt, 64-wide output rows (full 128B bf16 lines) ----
// out[c*ostride + r] = bf16(in[r*C + c]); tile 64 r x 32 c; XOR-swizzled LDS.
DI void transpose64_body(const float* __restrict__ in, u16* __restrict__ out,
                         int C, int ostride) {
  __shared__ float tile[32 * 65];
  int c0 = blockIdx.x * 32, r0 = blockIdx.y * 64;
  int t = threadIdx.x;
  int cc = t & 31, rr0 = t >> 5;
#pragma unroll
  for (int i = 0; i < 8; ++i) {
    int rr = rr0 + 8 * i;
    tile[cc * 65 + (rr ^ ((cc & 7) << 3))] = in[(long)(r0 + rr) * C + c0 + cc];
  }
  __syncthreads();
  int cj = t >> 3, rj = t & 7;
  u16x8 v;
#pragma unroll
  for (int k = 0; k < 8; ++k)
    v[k] = f2bf(tile[cj * 65 + ((rj * 8 + k) ^ ((cj & 7) << 3))]);
  *(u16x8*)(out + (long)(c0 + cj) * ostride + r0 + rj * 8) = v;
}

__global__ __launch_bounds__(256) void transpose64(
    const float* __restrict__ in, u16* __restrict__ out, int R, int C,
    int ostride) {
  in += (long)blockIdx.z * (long)R * C;
  out += (long)blockIdx.z * (long)C * ostride;
  transpose64_body(in, out, C, ostride);
}

struct TJob { const float* in; u16* out; int R; int ostride; };
struct TJobs { TJob j[6]; };
__global__ __launch_bounds__(256) void transpose64_multi(TJobs jobs) {
  TJob jb = jobs.j[blockIdx.z];                 // all jobs C = 1024
  if ((int)(blockIdx.y * 64) >= jb.R) return;
  transpose64_body(jb.in, jb.out, 1024, jb.ostride);
}

// ---------------- small MFMA GEMM: out = tanh(A0|A1 @ B^T), N=1024 ------
// Depth-2 pipelined (3 LDS buffers, counted vmcnt), raw barriers.
__global__ __launch_bounds__(256) void gemm_small(
    const u16* __restrict__ A0, const u16* __restrict__ A1,
    const u16* __restrict__ Bt, u16* __restrict__ outp,
    int M, int K, int kSplit, int Astride, int Bstride) {
  int mt = blockIdx.x, ntb = blockIdx.y;
  __shared__ __align__(16) u16 As[3][2048];   // [kg0..3][row0..63] x 8 u16
  __shared__ __align__(16) u16 Bs[3][4096];   // [kg0..3][col0..127] x 8 u16
  const int t = threadIdx.x;
  const int w = t >> 6, l = t & 63, lr = l & 15, lg = l >> 4;
  int ar = mt * 64 + (t & 63); if (ar >= M) ar = M - 1;
  const u16* pB = Bt + (long)(ntb * 128 + (t & 127)) * Bstride + (t >> 7) * 8;
  const int ntk = K >> 5;

  auto STG = [&](int buf, int kt) {
    int k0 = kt << 5;
    const u16* srcA = (k0 < kSplit)
        ? A0 + (long)ar * Astride + k0 + w * 8
        : A1 + (long)ar * 1024 + (k0 - kSplit) + w * 8;
    gload_lds16(srcA, &As[buf][w * 512]);
    gload_lds16(pB + k0, &Bs[buf][w * 512]);
    gload_lds16(pB + k0 + 16, &Bs[buf][2048 + w * 512]);
  };
  STG(0, 0);
  if (ntk > 1) STG(1, 1);

  f32x4 acc[4][2] = {};
  for (int kt = 0; kt < ntk; ++kt) {
    int cb = kt % 3;
    if (kt + 2 < ntk) {
      STG((kt + 2) % 3, kt + 2);
      asm volatile("s_waitcnt vmcnt(6)" ::: "memory");
    } else if (kt + 1 < ntk) {
      asm volatile("s_waitcnt vmcnt(3)" ::: "memory");
    } else {
      asm volatile("s_waitcnt vmcnt(0)" ::: "memory");
    }
    __builtin_amdgcn_s_barrier();
    __builtin_amdgcn_sched_barrier(0);
    bf16x8 a[4], b[2];
#pragma unroll
    for (int mf = 0; mf < 4; ++mf)
      a[mf] = *(const bf16x8*)(&As[cb][(lg * 64 + mf * 16 + lr) * 8]);
#pragma unroll
    for (int nf = 0; nf < 2; ++nf)
      b[nf] = *(const bf16x8*)(&Bs[cb][(lg * 128 + w * 32 + nf * 16 + lr) * 8]);
#pragma unroll
    for (int mf = 0; mf < 4; ++mf)
#pragma unroll
      for (int nf = 0; nf < 2; ++nf)
        acc[mf][nf] = __builtin_amdgcn_mfma_f32_16x16x32_bf16(a[mf], b[nf], acc[mf][nf], 0, 0, 0);
    __builtin_amdgcn_s_barrier();
    __builtin_amdgcn_sched_barrier(0);
  }
#pragma unroll
  for (int mf = 0; mf < 4; ++mf)
#pragma unroll
    for (int j = 0; j < 4; ++j) {
      int r = mt * 64 + mf * 16 + lg * 4 + j;
      if (r < M) {
        u16* o = outp + (long)r * 1024 + ntb * 128 + w * 32;
#pragma unroll
        for (int nf = 0; nf < 2; ++nf)
          o[nf * 16 + lr] = f2bf(tanhf(acc[mf][nf][j]));
      }
    }
}

// ---------------- mid GEMM (128x128, BK=32) for ctx / cur ----------------
template <int MODE>
__global__ __launch_bounds__(256) void gemm_bf16(
    const u16* __restrict__ A, const u16* __restrict__ Bt,
    const float* __restrict__ Ww, const int* __restrict__ xtok,
    void* __restrict__ outp, int M) {
  int mt = blockIdx.x, nt = blockIdx.y, mz = blockIdx.z;
  if constexpr (MODE == 0) Bt += (long)mz << 20;  // U slice [1024][1024]

  __shared__ __align__(16) u16 As[128 * 32];
  __shared__ __align__(16) u16 Bs[128 * 32];

  const int t = threadIdx.x;
  const int w = t >> 6, l = t & 63;
  const int lr = l & 15, lg = l >> 4;
  const int wr = w >> 1, wc = w & 1;

  int ar0 = mt * 128 + (t >> 2);
  int ar1 = ar0 + 64;
  if (ar0 >= M) ar0 = 0;
  if (ar1 >= M) ar1 = 0;
  long arow0, arow1;
  if constexpr (MODE == 1) {
    arow0 = (long)(ar0 / 31) * 32 + (ar0 % 31) + 1;
    arow1 = (long)(ar1 / 31) * 32 + (ar1 % 31) + 1;
  } else {
    arow0 = ar0; arow1 = ar1;
  }

  const u16* ga0 = A + arow0 * 1024 + (t & 3) * 8;
  const u16* ga1 = A + arow1 * 1024 + (t & 3) * 8;
  const u16* gb0 = Bt + ((long)nt * 128 + (t >> 2)) * 1024 + (t & 3) * 8;
  const u16* gb1 = gb0 + 64 * 1024;

  u16* dA0 = As + w * 512; u16* dA1 = As + 2048 + w * 512;
  u16* dB0 = Bs + w * 512; u16* dB1 = Bs + 2048 + w * 512;

  f32x4 acc[4][4] = {};

  for (int kt = 0; kt < 32; ++kt) {
    __syncthreads();
    gload_lds16(ga0, dA0); gload_lds16(ga1, dA1);
    gload_lds16(gb0, dB0); gload_lds16(gb1, dB1);
    ga0 += 32; ga1 += 32; gb0 += 32; gb1 += 32;
    __syncthreads();
    bf16x8 a[4], b[4];
#pragma unroll
    for (int m = 0; m < 4; ++m)
      a[m] = *(const bf16x8*)&As[(wr * 64 + m * 16 + lr) * 32 + lg * 8];
#pragma unroll
    for (int n = 0; n < 4; ++n)
      b[n] = *(const bf16x8*)&Bs[(wc * 64 + n * 16 + lr) * 32 + lg * 8];
#pragma unroll
    for (int m = 0; m < 4; ++m)
#pragma unroll
      for (int n = 0; n < 4; ++n)
        acc[m][n] = __builtin_amdgcn_mfma_f32_16x16x32_bf16(a[m], b[n], acc[m][n], 0, 0, 0);
  }

#pragma unroll
  for (int m = 0; m < 4; ++m) {
#pragma unroll
    for (int j = 0; j < 4; ++j) {
      int r = mt * 128 + wr * 64 + m * 16 + lg * 4 + j;
      if (r >= M) continue;
      if constexpr (MODE == 0) {
        u16* oc = (u16*)outp;
#pragma unroll
        for (int n = 0; n < 4; ++n) {
          int col = nt * 128 + wc * 64 + n * 16 + lr;
          oc[((long)r * 32 + mz) * 1024 + col] = f2bf(tanhf(acc[m][n][j]));
        }
      } else {
        int sb = r / 31, l1 = r % 31;
        int s = sb >> 6, b = sb & 63;
        int widx = xtok[b * 128 + (s + 1) * 32 + l1];
        const float* wwr = Ww + (long)widx * 1024;
        u16* oc = (u16*)outp;
#pragma unroll
        for (int n = 0; n < 4; ++n) {
          int col = nt * 128 + wc * 64 + n * 16 + lr;
          oc[(long)r * 1024 + col] = f2bf(tanhf(acc[m][n][j] + wwr[col]));
        }
      }
    }
  }
}

// ---------------- BIG GEMM: 128x128 tile, BK=32, 3-buf depth-2 ----------
// Scaled-up gemm_small template: 4 waves, 48 KB LDS -> 3 blocks/CU, counted
// vmcnt(8/4/0), 2 raw barriers per K-tile. K-major LDS [kg0..3][row/col]
// 16B units (conflict-free quarter-wave ds_read_b128; linear gload_lds).
// M = 6144 incl. pad rows 5952..6143 which emit the one-hot l=0 rows.
__global__ __launch_bounds__(256) void gemm_big(
    const u16* __restrict__ A, const u16* __restrict__ Bt,
    const int* __restrict__ x, float* __restrict__ out) {
  int bid = blockIdx.x;                       // 12000 = 8 * 1500
  int xcd = bid & 7, idx = bid >> 3;
  int nt = idx / 6;                           // 0..249
  int mt = xcd * 6 + idx % 6;                 // 0..47 (XCD owns 6 mt rows)

  __shared__ __align__(16) u16 lds3[3][8192]; // 3 x (A 8KB | B 8KB)

  const int t = threadIdx.x;
  const int w = t >> 6, l = t & 63;
  const int lr = l & 15, lg = l >> 4;
  const int wm = w >> 1, wn = w & 1;          // 2 x 2 waves, 64x64 each

  int arow = mt * 128 + (t & 127);
  if (arow > 5951) arow = 5951;               // pad rows: value ignored
  const u16* pA = A + (long)arow * 1024 + (t >> 7) * 8;
  const u16* pB = Bt + ((long)nt * 128 + (t & 127)) * 1024 + (t >> 7) * 8;

  auto STG = [&](int buf, int kt) {
    const u16* sa = pA + kt * 32;
    gload_lds16(sa,      &lds3[buf][w * 512]);
    gload_lds16(sa + 16, &lds3[buf][2048 + w * 512]);
    const u16* sb = pB + kt * 32;
    gload_lds16(sb,      &lds3[buf][4096 + w * 512]);
    gload_lds16(sb + 16, &lds3[buf][6144 + w * 512]);
  };
  STG(0, 0); STG(1, 1);

  f32x4 acc[4][4] = {};
  for (int kt = 0; kt < 32; ++kt) {
    int cb = kt % 3;
    if (kt + 2 < 32) {
      STG((kt + 2) % 3, kt + 2);
      asm volatile("s_waitcnt vmcnt(8)" ::: "memory");
    } else if (kt + 1 < 32) {
      asm volatile("s_waitcnt vmcnt(4)" ::: "memory");
    } else {
      asm volatile("s_waitcnt vmcnt(0)" ::: "memory");
    }
    __builtin_amdgcn_s_barrier();
    __builtin_amdgcn_sched_barrier(0);
    bf16x8 a[4], b[4];
#pragma unroll
    for (int mf = 0; mf < 4; ++mf)
      a[mf] = *(const bf16x8*)&lds3[cb][(lg * 128 + wm * 64 + mf * 16 + lr) * 8];
#pragma unroll
    for (int nf = 0; nf < 4; ++nf)
      b[nf] = *(const bf16x8*)&lds3[cb][4096 + (lg * 128 + wn * 64 + nf * 16 + lr) * 8];
    __builtin_amdgcn_s_setprio(1);
#pragma unroll
    for (int mf = 0; mf < 4; ++mf)
#pragma unroll
      for (int nf = 0; nf < 4; ++nf)
        acc[mf][nf] = __builtin_amdgcn_mfma_f32_16x16x32_bf16(a[mf], b[nf], acc[mf][nf], 0, 0, 0);
    __builtin_amdgcn_s_setprio(0);
    __builtin_amdgcn_s_barrier();
    __builtin_amdgcn_sched_barrier(0);
  }

  // epilogue: per-wave LDS transpose in TWO 64x32 passes (stride 33 f32,
  // no row overlap, <=2-way conflicts; 4 waves x 8448 B = 33.8 KB fits) ->
  // full 128B-line nontemporal dwordx4 stores; pad rows emit one-hot.
  __syncthreads();
  float* T = (float*)&lds3[0][0] + w * 2112;  // 64x33 f32 = 8448 B per wave
#pragma unroll
  for (int nh = 0; nh < 2; ++nh) {
#pragma unroll
    for (int mf = 0; mf < 4; ++mf)
#pragma unroll
      for (int j = 0; j < 4; ++j)
#pragma unroll
        for (int nf = 0; nf < 2; ++nf)
          T[(mf * 16 + lg * 4 + j) * 33 + nf * 16 + lr] =
              acc[mf][nh * 2 + nf][j];
#pragma unroll
    for (int i = 0; i < 8; ++i) {
      int row = (l >> 3) + 8 * i;
      int c4 = (l & 7) * 4;
      f32x4 v;
      v[0] = T[row * 33 + c4];     v[1] = T[row * 33 + c4 + 1];
      v[2] = T[row * 33 + c4 + 2]; v[3] = T[row * 33 + c4 + 3];
      int r = mt * 128 + wm * 64 + row;
      int colb = nt * 128 + wn * 64 + nh * 32 + c4;
      float* o;
      if (r < 5952) {
        int s = r / 1984, rem = r % 1984;
        int bb = rem / 31, l1 = rem % 31;
        o = out + ((long)bb * 96 + s * 32 + l1 + 1) * 32000 + colb;
      } else {
        int i2 = r - 5952;
        int s = i2 >> 6, bb = i2 & 63;
        int tok = x[bb * 128 + (s + 1) * 32];
        v[0] = (colb == tok);     v[1] = (colb + 1 == tok);
        v[2] = (colb + 2 == tok); v[3] = (colb + 3 == tok);
        o = out + ((long)bb * 96 + s * 32) * 32000 + colb;
      }
      __builtin_nontemporal_store(v, (f32x4*)o);
    }
  }
}

// ------------------------------- launch ---------------------------------
extern "C" void kernel_launch(void* const* d_in, const int* in_sizes, int n_in,
                              void* d_out, int out_size, void* d_ws, size_t ws_size,
                              hipStream_t stream) {
  const int*   x    = (const int*)d_in[0];
  const float* emb  = (const float*)d_in[2];
  const float* Wcsm = (const float*)d_in[3];
  const float* Wx1  = (const float*)d_in[4];
  const float* Wh1  = (const float*)d_in[5];
  const float* Wx2  = (const float*)d_in[6];
  const float* Wh2  = (const float*)d_in[7];
  const float* U    = (const float*)d_in[8];
  const float* Ww   = (const float*)d_in[9];
  const float* Wc   = (const float*)d_in[10];
  const float* Wfc  = (const float*)d_in[11];
  float* out = (float*)d_out;

  char* ws = (char*)d_ws;
  u16* sentM = (u16*)(ws + 0);          //  196608 [192][512]
  u16* sentH = (u16*)(ws + 196608);     //  393216 [192][1024]
  u16* h1a   = (u16*)(ws + 589824);     //  131072 [64][1024]
  u16* h1b   = (u16*)(ws + 720896);     //  131072
  u16* hsb   = (u16*)(ws + 851968);     //  393216 [192][1024]
  u16* ctx   = (u16*)(ws + 1245184);    // 12582912 [192*32][1024]
  u16* WcsmT = (u16*)(ws + 1245184);    //  1048576 [1024][512]   (pre-ctx)
  u16* WxhT1 = (u16*)(ws + 2293760);    //  4194304 [1024][2048]  (pre-ctx)
  u16* WxhT2 = (u16*)(ws + 6488064);    //  4194304 [1024][2048]  (pre-ctx)
  u16* cur   = (u16*)(ws + 13828096);   // 12189696 [5952][1024]
  u16* WcT   = (u16*)(ws + 26017792);   //  2097152 [1024][1024]
  u16* BIG   = (u16*)(ws + 28114944);   // 67108864 U^T then Wfc^T

  // all six [1024][1024/512] weight transposes in one launch
  TJobs jobs;
  jobs.j[0] = {Wx1,  WxhT1,        1024, 2048};
  jobs.j[1] = {Wh1,  WxhT1 + 1024, 1024, 2048};
  jobs.j[2] = {Wx2,  WxhT2,        1024, 2048};
  jobs.j[3] = {Wh2,  WxhT2 + 1024, 1024, 2048};
  jobs.j[4] = {Wc,   WcT,          1024, 1024};
  jobs.j[5] = {Wcsm, WcsmT,         512,  512};
  transpose64_multi<<<dim3(32, 16, 6), 256, 0, stream>>>(jobs);

  // CSM: mean-pool + tanh(sentM @ Wcsm)
  meanpool_k<<<192, 256, 0, stream>>>(x, emb, sentM);
  gemm_small<<<dim3(3, 8), 256, 0, stream>>>(sentM, sentM, WcsmT, sentH, 192, 512, 512, 512, 512);

  // RNN: h = tanh([x h] @ [Wx;Wh]) via concat-K; hs[s] lands in hsb rows s*64..
  gemm_small<<<dim3(1, 8), 256, 0, stream>>>(sentH,          h1a, WxhT1, h1a,           64, 1024, 1024, 1024, 2048);
  gemm_small<<<dim3(1, 8), 256, 0, stream>>>(h1a,            h1a, WxhT2, hsb,           64, 1024, 1024, 1024, 2048);
  gemm_small<<<dim3(1, 8), 256, 0, stream>>>(sentH + 65536,  h1a, WxhT1, h1b,           64, 2048, 1024, 1024, 2048);
  gemm_small<<<dim3(1, 8), 256, 0, stream>>>(h1b,            hsb, WxhT2, hsb + 65536,   64, 2048, 1024, 1024, 2048);
  gemm_small<<<dim3(1, 8), 256, 0, stream>>>(sentH + 131072, h1b, WxhT1, h1a,           64, 2048, 1024, 1024, 2048);
  gemm_small<<<dim3(1, 8), 256, 0, stream>>>(h1a, hsb + 65536, WxhT2, hsb + 131072,     64, 2048, 1024, 1024, 2048);

  // contexts: per-m GEMM against U[m]^T
  transpose64<<<dim3(32, 16, 32), 256, 0, stream>>>(U, BIG, 1024, 1024, 1024);
  gemm_bf16<0><<<dim3(2, 8, 32), 256, 0, stream>>>(hsb, BIG, nullptr, nullptr, (void*)ctx, 192);

  // cur: GEMM against Wc^T with Ww gather + tanh epilogue
  gemm_bf16<1><<<dim3(47, 8, 1), 256, 0, stream>>>(ctx, WcT, Ww, x, (void*)cur, 5952);

  // y_sec: 128^2 3-buf pipelined GEMM vs Wfc^T; writes ALL of d_out
  transpose64<<<dim3(1000, 16, 1), 256, 0, stream>>>(Wfc, BIG, 1024, 32000, 1024);
  gemm_big<<<12000, 256, 0, stream>>>(cur, BIG, x, out);
}

// Round 9
// 911.368 us; speedup vs baseline: 1.3134x; 1.2844x over previous
//
#include <hip/hip_runtime.h>
#include <math.h>

typedef __bf16 bf16x8 __attribute__((ext_vector_type(8)));
typedef float f32x4 __attribute__((ext_vector_type(4)));
typedef unsigned short u16;
typedef u16 u16x8 __attribute__((ext_vector_type(8)));

#define DI __device__ __forceinline__

DI u16 f2bf(float f) {
  union { float f; unsigned u; } v; v.f = f;
  unsigned r = v.u + 0x7FFFu + ((v.u >> 16) & 1u);  // RNE
  return (u16)(r >> 16);
}

DI void gload_lds16(const u16* g, u16* l) {
  // dest = wave-uniform base + lane*16B (HW semantics); src is per-lane.
  __builtin_amdgcn_global_load_lds(
      (const __attribute__((address_space(1))) unsigned int*)g,
      (__attribute__((address_space(3))) unsigned int*)l, 16, 0, 0);
}

// device-scope grid barrier (all blocks co-resident; counters pre-zeroed)
DI void grid_bar(int* ctr, int nblk) {
  __syncthreads();                 // drains each wave's vm/lgkm
  if (threadIdx.x == 0) {
    __threadfence();               // release: writeback to device scope
    atomicAdd(ctr, 1);
    while (atomicAdd(ctr, 0) < nblk) { __builtin_amdgcn_s_sleep(8); }
    __threadfence();               // acquire: invalidate local caches
  }
  __syncthreads();
}

// ---------------- mean-pool embeddings -> sentM [192][512] bf16 ---------
__global__ __launch_bounds__(256) void meanpool_k(const int* __restrict__ x,
    const float* __restrict__ emb, u16* __restrict__ sentM) {
  int bs = blockIdx.x; int s = bs >> 6, b = bs & 63;
  int t = threadIdx.x;
  float a0 = 0.f, a1 = 0.f;
  for (int lt = 0; lt < 32; ++lt) {
    int tok = x[b * 128 + s * 32 + lt];
    const float* e = emb + (long)tok * 512;
    a0 += e[t]; a1 += e[t + 256];
  }
  sentM[(long)bs * 512 + t] = f2bf(a0 * (1.f / 32.f));
  sentM[(long)bs * 512 + t + 256] = f2bf(a1 * (1.f / 32.f));
}

// ------- transpose + cvt, 64-wide output rows (full 128B bf16 lines) ----
DI void transpose64_body(const float* __restrict__ in, u16* __restrict__ out,
                         int C, int ostride) {
  __shared__ float tile[32 * 65];
  int c0 = blockIdx.x * 32, r0 = blockIdx.y * 64;
  int t = threadIdx.x;
  int cc = t & 31, rr0 = t >> 5;
#pragma unroll
  for (int i = 0; i < 8; ++i) {
    int rr = rr0 + 8 * i;
    tile[cc * 65 + (rr ^ ((cc & 7) << 3))] = in[(long)(r0 + rr) * C + c0 + cc];
  }
  __syncthreads();
  int cj = t >> 3, rj = t & 7;
  u16x8 v;
#pragma unroll
  for (int k = 0; k < 8; ++k)
    v[k] = f2bf(tile[cj * 65 + ((rj * 8 + k) ^ ((cj & 7) << 3))]);
  *(u16x8*)(out + (long)(c0 + cj) * ostride + r0 + rj * 8) = v;
}

__global__ __launch_bounds__(256) void transpose64(
    const float* __restrict__ in, u16* __restrict__ out, int R, int C,
    int ostride) {
  in += (long)blockIdx.z * (long)R * C;
  out += (long)blockIdx.z * (long)C * ostride;
  transpose64_body(in, out, C, ostride);
}

struct TJob { const float* in; u16* out; int R; int ostride; };
struct TJobs { TJob j[6]; };
__global__ __launch_bounds__(256) void transpose64_multi(TJobs jobs) {
  TJob jb = jobs.j[blockIdx.z];                 // all jobs C = 1024
  if ((int)(blockIdx.y * 64) >= jb.R) return;
  transpose64_body(jb.in, jb.out, 1024, jb.ostride);
}

// -------- small GEMM body: out = tanh(A0|A1 @ B^T), N=1024, 64xM tile ---
// Depth-2 pipelined (3 LDS buffers, counted vmcnt), raw barriers.
DI void small_body(u16 (*As)[2048], u16 (*Bs)[4096],
                   const u16* A0, const u16* A1, const u16* Bt, u16* outp,
                   int M, int K, int kSplit, int Astride, int Bstride,
                   int mt, int ntb) {
  const int t = threadIdx.x;
  const int w = t >> 6, l = t & 63, lr = l & 15, lg = l >> 4;
  int ar = mt * 64 + (t & 63); if (ar >= M) ar = M - 1;
  const u16* pB = Bt + (long)(ntb * 128 + (t & 127)) * Bstride + (t >> 7) * 8;
  const int ntk = K >> 5;

  auto STG = [&](int buf, int kt) {
    int k0 = kt << 5;
    const u16* srcA = (k0 < kSplit)
        ? A0 + (long)ar * Astride + k0 + w * 8
        : A1 + (long)ar * 1024 + (k0 - kSplit) + w * 8;
    gload_lds16(srcA, &As[buf][w * 512]);
    gload_lds16(pB + k0, &Bs[buf][w * 512]);
    gload_lds16(pB + k0 + 16, &Bs[buf][2048 + w * 512]);
  };
  STG(0, 0);
  if (ntk > 1) STG(1, 1);

  f32x4 acc[4][2] = {};
  for (int kt = 0; kt < ntk; ++kt) {
    int cb = kt % 3;
    if (kt + 2 < ntk) {
      STG((kt + 2) % 3, kt + 2);
      asm volatile("s_waitcnt vmcnt(6)" ::: "memory");
    } else if (kt + 1 < ntk) {
      asm volatile("s_waitcnt vmcnt(3)" ::: "memory");
    } else {
      asm volatile("s_waitcnt vmcnt(0)" ::: "memory");
    }
    __builtin_amdgcn_s_barrier();
    __builtin_amdgcn_sched_barrier(0);
    bf16x8 a[4], b[2];
#pragma unroll
    for (int mf = 0; mf < 4; ++mf)
      a[mf] = *(const bf16x8*)(&As[cb][(lg * 64 + mf * 16 + lr) * 8]);
#pragma unroll
    for (int nf = 0; nf < 2; ++nf)
      b[nf] = *(const bf16x8*)(&Bs[cb][(lg * 128 + w * 32 + nf * 16 + lr) * 8]);
#pragma unroll
    for (int mf = 0; mf < 4; ++mf)
#pragma unroll
      for (int nf = 0; nf < 2; ++nf)
        acc[mf][nf] = __builtin_amdgcn_mfma_f32_16x16x32_bf16(a[mf], b[nf], acc[mf][nf], 0, 0, 0);
    __builtin_amdgcn_s_barrier();
    __builtin_amdgcn_sched_barrier(0);
  }
#pragma unroll
  for (int mf = 0; mf < 4; ++mf)
#pragma unroll
    for (int j = 0; j < 4; ++j) {
      int r = mt * 64 + mf * 16 + lg * 4 + j;
      if (r < M) {
        u16* o = outp + (long)r * 1024 + ntb * 128 + w * 32;
#pragma unroll
        for (int nf = 0; nf < 2; ++nf)
          o[nf * 16 + lr] = f2bf(tanhf(acc[mf][nf][j]));
      }
    }
}

// ---- fused CSM + 6 RNN steps: one kernel, 24 co-resident blocks --------
__global__ __launch_bounds__(256) void rnn_chain(
    const u16* __restrict__ sentM, u16* __restrict__ sentH,
    u16* __restrict__ h1a, u16* __restrict__ h1b, u16* __restrict__ hsb,
    const u16* __restrict__ WcsmT, const u16* __restrict__ WxhT1,
    const u16* __restrict__ WxhT2, int* __restrict__ ctr) {
  __shared__ __align__(16) u16 As[3][2048];
  __shared__ __align__(16) u16 Bs[3][4096];
  int b = blockIdx.x;
  // step 0: sentH = tanh(sentM @ Wcsm)   (M=192, 24 blocks)
  small_body(As, Bs, sentM, sentM, WcsmT, sentH, 192, 512, 512, 512, 512,
             b >> 3, b & 7);
  grid_bar(ctr + 0, 24);
  if (b < 8) small_body(As, Bs, sentH, h1a, WxhT1, h1a,
                        64, 1024, 1024, 1024, 2048, 0, b);
  grid_bar(ctr + 1, 24);
  if (b < 8) small_body(As, Bs, h1a, h1a, WxhT2, hsb,
                        64, 1024, 1024, 1024, 2048, 0, b);
  grid_bar(ctr + 2, 24);
  if (b < 8) small_body(As, Bs, sentH + 65536, h1a, WxhT1, h1b,
                        64, 2048, 1024, 1024, 2048, 0, b);
  grid_bar(ctr + 3, 24);
  if (b < 8) small_body(As, Bs, h1b, hsb, WxhT2, hsb + 65536,
                        64, 2048, 1024, 1024, 2048, 0, b);
  grid_bar(ctr + 4, 24);
  if (b < 8) small_body(As, Bs, sentH + 131072, h1b, WxhT1, h1a,
                        64, 2048, 1024, 1024, 2048, 0, b);
  grid_bar(ctr + 5, 24);
  if (b < 8) small_body(As, Bs, h1a, hsb + 65536, WxhT2, hsb + 131072,
                        64, 2048, 1024, 1024, 2048, 0, b);
}

// ---------------- mid GEMM (128x128, BK=32) for ctx / cur ----------------
template <int MODE>
__global__ __launch_bounds__(256) void gemm_bf16(
    const u16* __restrict__ A, const u16* __restrict__ Bt,
    const float* __restrict__ Ww, const int* __restrict__ xtok,
    void* __restrict__ outp, int M) {
  int mt = blockIdx.x, nt = blockIdx.y, mz = blockIdx.z;
  if constexpr (MODE == 0) Bt += (long)mz << 20;  // U slice [1024][1024]

  __shared__ __align__(16) u16 As[128 * 32];
  __shared__ __align__(16) u16 Bs[128 * 32];

  const int t = threadIdx.x;
  const int w = t >> 6, l = t & 63;
  const int lr = l & 15, lg = l >> 4;
  const int wr = w >> 1, wc = w & 1;

  int ar0 = mt * 128 + (t >> 2);
  int ar1 = ar0 + 64;
  if (ar0 >= M) ar0 = 0;
  if (ar1 >= M) ar1 = 0;
  long arow0, arow1;
  if constexpr (MODE == 1) {
    arow0 = (long)(ar0 / 31) * 32 + (ar0 % 31) + 1;
    arow1 = (long)(ar1 / 31) * 32 + (ar1 % 31) + 1;
  } else {
    arow0 = ar0; arow1 = ar1;
  }

  const u16* ga0 = A + arow0 * 1024 + (t & 3) * 8;
  const u16* ga1 = A + arow1 * 1024 + (t & 3) * 8;
  const u16* gb0 = Bt + ((long)nt * 128 + (t >> 2)) * 1024 + (t & 3) * 8;
  const u16* gb1 = gb0 + 64 * 1024;

  u16* dA0 = As + w * 512; u16* dA1 = As + 2048 + w * 512;
  u16* dB0 = Bs + w * 512; u16* dB1 = Bs + 2048 + w * 512;

  f32x4 acc[4][4] = {};

  for (int kt = 0; kt < 32; ++kt) {
    __syncthreads();
    gload_lds16(ga0, dA0); gload_lds16(ga1, dA1);
    gload_lds16(gb0, dB0); gload_lds16(gb1, dB1);
    ga0 += 32; ga1 += 32; gb0 += 32; gb1 += 32;
    __syncthreads();
    bf16x8 a[4], b[4];
#pragma unroll
    for (int m = 0; m < 4; ++m)
      a[m] = *(const bf16x8*)&As[(wr * 64 + m * 16 + lr) * 32 + lg * 8];
#pragma unroll
    for (int n = 0; n < 4; ++n)
      b[n] = *(const bf16x8*)&Bs[(wc * 64 + n * 16 + lr) * 32 + lg * 8];
#pragma unroll
    for (int m = 0; m < 4; ++m)
#pragma unroll
      for (int n = 0; n < 4; ++n)
        acc[m][n] = __builtin_amdgcn_mfma_f32_16x16x32_bf16(a[m], b[n], acc[m][n], 0, 0, 0);
  }

#pragma unroll
  for (int m = 0; m < 4; ++m) {
#pragma unroll
    for (int j = 0; j < 4; ++j) {
      int r = mt * 128 + wr * 64 + m * 16 + lg * 4 + j;
      if (r >= M) continue;
      if constexpr (MODE == 0) {
        u16* oc = (u16*)outp;
#pragma unroll
        for (int n = 0; n < 4; ++n) {
          int col = nt * 128 + wc * 64 + n * 16 + lr;
          oc[((long)r * 32 + mz) * 1024 + col] = f2bf(tanhf(acc[m][n][j]));
        }
      } else {
        int sb = r / 31, l1 = r % 31;
        int s = sb >> 6, b = sb & 63;
        int widx = xtok[b * 128 + (s + 1) * 32 + l1];
        const float* wwr = Ww + (long)widx * 1024;
        u16* oc = (u16*)outp;
#pragma unroll
        for (int n = 0; n < 4; ++n) {
          int col = nt * 128 + wc * 64 + n * 16 + lr;
          oc[(long)r * 1024 + col] = f2bf(tanhf(acc[m][n][j] + wwr[col]));
        }
      }
    }
  }
}

// ---------------- BIG GEMM: persistent 256x256, BK=64, 8-phase ----------
// Grid 256 (1 block/CU); each block loops 11-12 tiles so tile i's NT-store
// drain overlaps tile i+1's prologue + first phases (VM4 subsumes stores:
// in-order retirement drains older stores before the awaited loads).
// Pad rows 5952..6143 emit the one-hot l=0 rows.
#define NOSTAGE ((void)0)
#define VM4 asm volatile("s_waitcnt vmcnt(4)" ::: "memory")
#define VM0 asm volatile("s_waitcnt vmcnt(0)" ::: "memory")

#define STAGE_A(H, KT) do {                                                \
    const u16* _s = ((H) ? pA1 : pA0) + (KT) * 64;                         \
    u16* _d = lds + ((KT) & 1) * 16384 + (H) * 8192 + w * 512;             \
    gload_lds16(_s, _d); gload_lds16(_s + 32, _d + 4096);                  \
  } while (0)
#define STAGE_B(H, KT) do {                                                \
    const u16* _s = ((H) ? pB1 : pB0) + (KT) * 64;                         \
    u16* _d = lds + 32768 + ((KT) & 1) * 16384 + (H) * 8192 + w * 512;     \
    gload_lds16(_s, _d); gload_lds16(_s + 32, _d + 4096);                  \
  } while (0)

#define PHASE(ABASE, MH, NH, RA, RB, STAGESTMT, WAITSTMT) do {             \
    if (RA) {                                                              \
      _Pragma("unroll") for (int ks = 0; ks < 2; ++ks)                     \
      _Pragma("unroll") for (int mf = 0; mf < 4; ++mf)                     \
        a[mf][ks] = *(const bf16x8*)(lds + (ABASE) + (MH) * 8192 + laneA + \
                                     ks * 4096 + mf * 128);                \
    }                                                                      \
    if (RB) {                                                              \
      _Pragma("unroll") for (int ks = 0; ks < 2; ++ks)                     \
      _Pragma("unroll") for (int nf = 0; nf < 2; ++nf)                     \
        b[NH][nf][ks] = *(const bf16x8*)(lds + 32768 + (ABASE) +           \
                                         (NH) * 8192 + laneB +             \
                                         ks * 4096 + nf * 128);            \
    }                                                                      \
    STAGESTMT;                                                             \
    __builtin_amdgcn_s_barrier();                                          \
    asm volatile("s_waitcnt lgkmcnt(0)" ::: "memory");                     \
    __builtin_amdgcn_sched_barrier(0);                                     \
    __builtin_amdgcn_s_setprio(1);                                         \
    _Pragma("unroll") for (int ks = 0; ks < 2; ++ks)                       \
    _Pragma("unroll") for (int mf = 0; mf < 4; ++mf)                       \
    _Pragma("unroll") for (int nf = 0; nf < 2; ++nf)                       \
      acc[(MH) * 4 + mf][(NH) * 2 + nf] =                                  \
          __builtin_amdgcn_mfma_f32_16x16x32_bf16(                         \
              a[mf][ks], b[NH][nf][ks],                                    \
              acc[(MH) * 4 + mf][(NH) * 2 + nf], 0, 0, 0);                 \
    __builtin_amdgcn_s_setprio(0);                                         \
    WAITSTMT;                                                              \
    __builtin_amdgcn_s_barrier();                                          \
  } while (0)

__global__ __launch_bounds__(512, 2) void gemm_big(
    const u16* __restrict__ A, const u16* __restrict__ Bt,
    const int* __restrict__ x, float* __restrict__ out) {
  __shared__ __align__(16) u16 lds[65536];    // A [0,32768) | B [32768,65536) u16

  const int t = threadIdx.x;
  const int w = t >> 6, l = t & 63;
  const int lr = l & 15, lg = l >> 4;
  const int wm = w >> 2, wn = w & 3;          // 2 x 4 waves
  const int laneA = (lg * 128 + wm * 64 + lr) * 8;
  const int laneB = (lg * 128 + wn * 32 + lr) * 8;

  int xcd = blockIdx.x & 7, slot = blockIdx.x >> 3;   // 8 x 32

  for (int tl = slot; tl < 375; tl += 32) {
    int nt = tl / 3;                          // 0..124
    int mt = xcd * 3 + tl % 3;                // XCD owns 3 mt rows

    int arow0 = mt * 256 + (t & 127);
    int arow1 = arow0 + 128;
    int ar0c = arow0 > 5951 ? 5951 : arow0;   // pad rows: value ignored
    int ar1c = arow1 > 5951 ? 5951 : arow1;
    const u16* pA0 = A + (long)ar0c * 1024 + (t >> 7) * 8;
    const u16* pA1 = A + (long)ar1c * 1024 + (t >> 7) * 8;
    const u16* pB0 = Bt + ((long)nt * 256 + (t & 127)) * 1024 + (t >> 7) * 8;
    const u16* pB1 = pB0 + 128 * 1024;

    f32x4 acc[8][4] = {};
    bf16x8 a[4][2], b[2][2][2];

    // prologue (VM4 also drains prior tile's stores — in-order retirement)
    STAGE_A(0, 0); STAGE_B(0, 0); STAGE_B(1, 0); STAGE_A(1, 0);
    STAGE_A(0, 1); STAGE_B(0, 1);
    VM4;
    __builtin_amdgcn_s_barrier();

    for (int g = 0; g < 14; g += 2) {
      PHASE(0,     0, 0, 1, 1, STAGE_B(1, g + 1), NOSTAGE);
      PHASE(0,     0, 1, 0, 1, STAGE_A(1, g + 1), NOSTAGE);
      PHASE(0,     1, 0, 1, 0, STAGE_A(0, g + 2), NOSTAGE);
      PHASE(0,     1, 1, 0, 0, STAGE_B(0, g + 2), VM4);
      PHASE(16384, 0, 0, 1, 1, STAGE_B(1, g + 2), NOSTAGE);
      PHASE(16384, 0, 1, 0, 1, STAGE_A(1, g + 2), NOSTAGE);
      PHASE(16384, 1, 0, 1, 0, STAGE_A(0, g + 3), NOSTAGE);
      PHASE(16384, 1, 1, 0, 0, STAGE_B(0, g + 3), VM4);
    }
    // group 14 (buf 0): stage tile 15's trailing halves
    PHASE(0,     0, 0, 1, 1, STAGE_B(1, 15), NOSTAGE);
    PHASE(0,     0, 1, 0, 1, STAGE_A(1, 15), NOSTAGE);
    PHASE(0,     1, 0, 1, 0, NOSTAGE, NOSTAGE);
    PHASE(0,     1, 1, 0, 0, NOSTAGE, VM0);
    // group 15 (buf 1): pure drain
    PHASE(16384, 0, 0, 1, 1, NOSTAGE, NOSTAGE);
    PHASE(16384, 0, 1, 0, 1, NOSTAGE, NOSTAGE);
    PHASE(16384, 1, 0, 1, 0, NOSTAGE, NOSTAGE);
    PHASE(16384, 1, 1, 0, 0, NOSTAGE, NOSTAGE);

    // epilogue: per-wave LDS transpose -> 128B-line NT dwordx4; stores are
    // issued but NOT drained here (next prologue's VM4 handles it).
    float* T = (float*)lds + w * 2112;
#pragma unroll
    for (int mh = 0; mh < 2; ++mh)
#pragma unroll
      for (int nh = 0; nh < 2; ++nh) {
#pragma unroll
        for (int mf = 0; mf < 4; ++mf)
#pragma unroll
          for (int j = 0; j < 4; ++j)
#pragma unroll
            for (int nf = 0; nf < 2; ++nf)
              T[(mf * 16 + lg * 4 + j) * 33 + nf * 16 + lr] =
                  acc[mh * 4 + mf][nh * 2 + nf][j];
#pragma unroll
        for (int i = 0; i < 8; ++i) {
          int row = (l >> 3) + 8 * i;
          int c4 = (l & 7) * 4;
          f32x4 v;
          v[0] = T[row * 33 + c4];     v[1] = T[row * 33 + c4 + 1];
          v[2] = T[row * 33 + c4 + 2]; v[3] = T[row * 33 + c4 + 3];
          int r = mt * 256 + mh * 128 + wm * 64 + row;
          int colb = nt * 256 + nh * 128 + wn * 32 + c4;
          float* o;
          if (r < 5952) {
            int s = r / 1984, rem = r % 1984;
            int bb = rem / 31, l1 = rem % 31;
            o = out + ((long)bb * 96 + s * 32 + l1 + 1) * 32000 + colb;
          } else {
            int i2 = r - 5952;
            int s = i2 >> 6, bb = i2 & 63;
            int tok = x[bb * 128 + (s + 1) * 32];
            v[0] = (colb == tok);     v[1] = (colb + 1 == tok);
            v[2] = (colb + 2 == tok); v[3] = (colb + 3 == tok);
            o = out + ((long)bb * 96 + s * 32) * 32000 + colb;
          }
          __builtin_nontemporal_store(v, (f32x4*)o);
        }
      }
    // all waves' T-reads are complete before their stores issued; barrier
    // so no wave's next-tile gload_lds overwrites T while others read.
    __builtin_amdgcn_s_barrier();
  }
}

// ------------------------------- launch ---------------------------------
extern "C" void kernel_launch(void* const* d_in, const int* in_sizes, int n_in,
                              void* d_out, int out_size, void* d_ws, size_t ws_size,
                              hipStream_t stream) {
  const int*   x    = (const int*)d_in[0];
  const float* emb  = (const float*)d_in[2];
  const float* Wcsm = (const float*)d_in[3];
  const float* Wx1  = (const float*)d_in[4];
  const float* Wh1  = (const float*)d_in[5];
  const float* Wx2  = (const float*)d_in[6];
  const float* Wh2  = (const float*)d_in[7];
  const float* U    = (const float*)d_in[8];
  const float* Ww   = (const float*)d_in[9];
  const float* Wc   = (const float*)d_in[10];
  const float* Wfc  = (const float*)d_in[11];
  float* out = (float*)d_out;

  char* ws = (char*)d_ws;
  u16* sentM = (u16*)(ws + 0);          //  196608 [192][512]
  u16* sentH = (u16*)(ws + 196608);     //  393216 [192][1024]
  u16* h1a   = (u16*)(ws + 589824);     //  131072 [64][1024]
  u16* h1b   = (u16*)(ws + 720896);     //  131072
  u16* hsb   = (u16*)(ws + 851968);     //  393216 [192][1024]
  u16* ctx   = (u16*)(ws + 1245184);    // 12582912 [192*32][1024]
  u16* WcsmT = (u16*)(ws + 1245184);    //  1048576 [1024][512]   (pre-ctx)
  u16* WxhT1 = (u16*)(ws + 2293760);    //  4194304 [1024][2048]  (pre-ctx)
  u16* WxhT2 = (u16*)(ws + 6488064);    //  4194304 [1024][2048]  (pre-ctx)
  u16* cur   = (u16*)(ws + 13828096);   // 12189696 [5952][1024]
  u16* WcT   = (u16*)(ws + 26017792);   //  2097152 [1024][1024]
  u16* BIG   = (u16*)(ws + 28114944);   // 67108864 U^T then Wfc^T
  // barrier counters live in the tail of BIG (dead during rnn_chain)
  int* ctr   = (int*)(ws + 28114944 + 67108864 - 64);

  // all six [1024][1024/512] weight transposes in one launch
  TJobs jobs;
  jobs.j[0] = {Wx1,  WxhT1,        1024, 2048};
  jobs.j[1] = {Wh1,  WxhT1 + 1024, 1024, 2048};
  jobs.j[2] = {Wx2,  WxhT2,        1024, 2048};
  jobs.j[3] = {Wh2,  WxhT2 + 1024, 1024, 2048};
  jobs.j[4] = {Wc,   WcT,          1024, 1024};
  jobs.j[5] = {Wcsm, WcsmT,         512,  512};
  transpose64_multi<<<dim3(32, 16, 6), 256, 0, stream>>>(jobs);

  // CSM mean-pool, then fused CSM-GEMM + 6 RNN steps in ONE kernel
  meanpool_k<<<192, 256, 0, stream>>>(x, emb, sentM);
  hipMemsetAsync((void*)ctr, 0, 64, stream);
  rnn_chain<<<24, 256, 0, stream>>>(sentM, sentH, h1a, h1b, hsb,
                                    WcsmT, WxhT1, WxhT2, ctr);

  // contexts: per-m GEMM against U[m]^T
  transpose64<<<dim3(32, 16, 32), 256, 0, stream>>>(U, BIG, 1024, 1024, 1024);
  gemm_bf16<0><<<dim3(2, 8, 32), 256, 0, stream>>>(hsb, BIG, nullptr, nullptr, (void*)ctx, 192);

  // cur: GEMM against Wc^T with Ww gather + tanh epilogue
  gemm_bf16<1><<<dim3(47, 8, 1), 256, 0, stream>>>(ctx, WcT, Ww, x, (void*)cur, 5952);

  // y_sec: persistent 8-phase 256^2 GEMM vs Wfc^T; writes ALL of d_out
  transpose64<<<dim3(1000, 16, 1), 256, 0, stream>>>(Wfc, BIG, 1024, 32000, 1024);
  gemm_big<<<256, 512, 0, stream>>>(cur, BIG, x, out);
}

// Round 10
// 825.299 us; speedup vs baseline: 1.4503x; 1.1043x over previous
//
#include <hip/hip_runtime.h>
#include <math.h>

typedef __bf16 bf16x8 __attribute__((ext_vector_type(8)));
typedef float f32x4 __attribute__((ext_vector_type(4)));
typedef unsigned short u16;
typedef unsigned char u8;
typedef u16 u16x8 __attribute__((ext_vector_type(8)));
typedef u8 u8x8 __attribute__((ext_vector_type(8)));

#define DI __device__ __forceinline__

DI u16 f2bf(float f) {
  union { float f; unsigned u; } v; v.f = f;
  unsigned r = v.u + 0x7FFFu + ((v.u >> 16) & 1u);  // RNE
  return (u16)(r >> 16);
}

DI u8 f2fp8(float f) {  // e4m3fn, RNE, FTZ, clamp to +-448
  union { float f; unsigned u; } v; v.f = f;
  unsigned s = (v.u >> 24) & 0x80u;
  unsigned au = v.u & 0x7FFFFFFFu;
  unsigned r = au + 0x7FFFFu + ((au >> 20) & 1u);   // RNE at 3-bit mantissa
  int e = (int)(r >> 23) - 120;                     // e4m3 biased exponent
  unsigned m = (r >> 20) & 7u;
  if (e <= 0) return (u8)s;                         // FTZ
  if (e > 15 || (e == 15 && m == 7)) return (u8)(s | 0x7E);  // clamp 448
  return (u8)(s | ((unsigned)e << 3) | m);
}

DI void gload_lds16(const void* g, void* l) {
  // dest = wave-uniform base + lane*16B (HW semantics); src is per-lane.
  __builtin_amdgcn_global_load_lds(
      (const __attribute__((address_space(1))) unsigned int*)g,
      (__attribute__((address_space(3))) unsigned int*)l, 16, 0, 0);
}

// device-scope grid barrier (all blocks co-resident; counters pre-zeroed)
DI void grid_bar(int* ctr, int nblk) {
  __syncthreads();
  if (threadIdx.x == 0) {
    __threadfence();
    atomicAdd(ctr, 1);
    while (atomicAdd(ctr, 0) < nblk) { __builtin_amdgcn_s_sleep(8); }
    __threadfence();
  }
  __syncthreads();
}

// ---------------- mean-pool embeddings -> sentM [192][512] bf16 ---------
__global__ __launch_bounds__(256) void meanpool_k(const int* __restrict__ x,
    const float* __restrict__ emb, u16* __restrict__ sentM) {
  int bs = blockIdx.x; int s = bs >> 6, b = bs & 63;
  int t = threadIdx.x;
  float a0 = 0.f, a1 = 0.f;
  for (int lt = 0; lt < 32; ++lt) {
    int tok = x[b * 128 + s * 32 + lt];
    const float* e = emb + (long)tok * 512;
    a0 += e[t]; a1 += e[t + 256];
  }
  sentM[(long)bs * 512 + t] = f2bf(a0 * (1.f / 32.f));
  sentM[(long)bs * 512 + t + 256] = f2bf(a1 * (1.f / 32.f));
}

// ------- transpose + cvt, 64-wide output rows (full 128B bf16 lines) ----
DI void transpose64_body(const float* __restrict__ in, u16* __restrict__ out,
                         int C, int ostride) {
  __shared__ float tile[32 * 65];
  int c0 = blockIdx.x * 32, r0 = blockIdx.y * 64;
  int t = threadIdx.x;
  int cc = t & 31, rr0 = t >> 5;
#pragma unroll
  for (int i = 0; i < 8; ++i) {
    int rr = rr0 + 8 * i;
    tile[cc * 65 + (rr ^ ((cc & 7) << 3))] = in[(long)(r0 + rr) * C + c0 + cc];
  }
  __syncthreads();
  int cj = t >> 3, rj = t & 7;
  u16x8 v;
#pragma unroll
  for (int k = 0; k < 8; ++k)
    v[k] = f2bf(tile[cj * 65 + ((rj * 8 + k) ^ ((cj & 7) << 3))]);
  *(u16x8*)(out + (long)(c0 + cj) * ostride + r0 + rj * 8) = v;
}

__global__ __launch_bounds__(256) void transpose64(
    const float* __restrict__ in, u16* __restrict__ out, int R, int C,
    int ostride) {
  in += (long)blockIdx.z * (long)R * C;
  out += (long)blockIdx.z * (long)C * ostride;
  transpose64_body(in, out, C, ostride);
}

struct TJob { const float* in; u16* out; int R; int ostride; };
struct TJobs { TJob j[6]; };
__global__ __launch_bounds__(256) void transpose64_multi(TJobs jobs) {
  TJob jb = jobs.j[blockIdx.z];                 // all jobs C = 1024
  if ((int)(blockIdx.y * 64) >= jb.R) return;
  transpose64_body(jb.in, jb.out, 1024, jb.ostride);
}

// ------- fp8 transpose: out[c][r] = fp8(16 * in[r][c]) -------------------
__global__ __launch_bounds__(256) void transpose64_f8(
    const float* __restrict__ in, u8* __restrict__ out, int C, int ostride) {
  __shared__ float tile[32 * 65];
  int c0 = blockIdx.x * 32, r0 = blockIdx.y * 64;
  int t = threadIdx.x;
  int cc = t & 31, rr0 = t >> 5;
#pragma unroll
  for (int i = 0; i < 8; ++i) {
    int rr = rr0 + 8 * i;
    tile[cc * 65 + (rr ^ ((cc & 7) << 3))] = in[(long)(r0 + rr) * C + c0 + cc];
  }
  __syncthreads();
  int cj = t >> 3, rj = t & 7;
  u8x8 v;
#pragma unroll
  for (int k = 0; k < 8; ++k)
    v[k] = f2fp8(16.f * tile[cj * 65 + ((rj * 8 + k) ^ ((cj & 7) << 3))]);
  *(u8x8*)(out + (long)(c0 + cj) * ostride + r0 + rj * 8) = v;
}

// -------- small GEMM body: out = tanh(A0|A1 @ B^T), N=1024, 64xM tile ---
DI void small_body(u16 (*As)[2048], u16 (*Bs)[4096],
                   const u16* A0, const u16* A1, const u16* Bt, u16* outp,
                   int M, int K, int kSplit, int Astride, int Bstride,
                   int mt, int ntb) {
  const int t = threadIdx.x;
  const int w = t >> 6, l = t & 63, lr = l & 15, lg = l >> 4;
  int ar = mt * 64 + (t & 63); if (ar >= M) ar = M - 1;
  const u16* pB = Bt + (long)(ntb * 128 + (t & 127)) * Bstride + (t >> 7) * 8;
  const int ntk = K >> 5;

  auto STG = [&](int buf, int kt) {
    int k0 = kt << 5;
    const u16* srcA = (k0 < kSplit)
        ? A0 + (long)ar * Astride + k0 + w * 8
        : A1 + (long)ar * 1024 + (k0 - kSplit) + w * 8;
    gload_lds16(srcA, &As[buf][w * 512]);
    gload_lds16(pB + k0, &Bs[buf][w * 512]);
    gload_lds16(pB + k0 + 16, &Bs[buf][2048 + w * 512]);
  };
  STG(0, 0);
  if (ntk > 1) STG(1, 1);

  f32x4 acc[4][2] = {};
  for (int kt = 0; kt < ntk; ++kt) {
    int cb = kt % 3;
    if (kt + 2 < ntk) {
      STG((kt + 2) % 3, kt + 2);
      asm volatile("s_waitcnt vmcnt(6)" ::: "memory");
    } else if (kt + 1 < ntk) {
      asm volatile("s_waitcnt vmcnt(3)" ::: "memory");
    } else {
      asm volatile("s_waitcnt vmcnt(0)" ::: "memory");
    }
    __builtin_amdgcn_s_barrier();
    __builtin_amdgcn_sched_barrier(0);
    bf16x8 a[4], b[2];
#pragma unroll
    for (int mf = 0; mf < 4; ++mf)
      a[mf] = *(const bf16x8*)(&As[cb][(lg * 64 + mf * 16 + lr) * 8]);
#pragma unroll
    for (int nf = 0; nf < 2; ++nf)
      b[nf] = *(const bf16x8*)(&Bs[cb][(lg * 128 + w * 32 + nf * 16 + lr) * 8]);
#pragma unroll
    for (int mf = 0; mf < 4; ++mf)
#pragma unroll
      for (int nf = 0; nf < 2; ++nf)
        acc[mf][nf] = __builtin_amdgcn_mfma_f32_16x16x32_bf16(a[mf], b[nf], acc[mf][nf], 0, 0, 0);
    __builtin_amdgcn_s_barrier();
    __builtin_amdgcn_sched_barrier(0);
  }
#pragma unroll
  for (int mf = 0; mf < 4; ++mf)
#pragma unroll
    for (int j = 0; j < 4; ++j) {
      int r = mt * 64 + mf * 16 + lg * 4 + j;
      if (r < M) {
        u16* o = outp + (long)r * 1024 + ntb * 128 + w * 32;
#pragma unroll
        for (int nf = 0; nf < 2; ++nf)
          o[nf * 16 + lr] = f2bf(tanhf(acc[mf][nf][j]));
      }
    }
}

// ---- fused CSM + 6 RNN steps: one kernel, 24 co-resident blocks --------
__global__ __launch_bounds__(256) void rnn_chain(
    const u16* __restrict__ sentM, u16* __restrict__ sentH,
    u16* __restrict__ h1a, u16* __restrict__ h1b, u16* __restrict__ hsb,
    const u16* __restrict__ WcsmT, const u16* __restrict__ WxhT1,
    const u16* __restrict__ WxhT2, int* __restrict__ ctr) {
  __shared__ __align__(16) u16 As[3][2048];
  __shared__ __align__(16) u16 Bs[3][4096];
  int b = blockIdx.x;
  small_body(As, Bs, sentM, sentM, WcsmT, sentH, 192, 512, 512, 512, 512,
             b >> 3, b & 7);
  grid_bar(ctr + 0, 24);
  if (b < 8) small_body(As, Bs, sentH, h1a, WxhT1, h1a,
                        64, 1024, 1024, 1024, 2048, 0, b);
  grid_bar(ctr + 1, 24);
  if (b < 8) small_body(As, Bs, h1a, h1a, WxhT2, hsb,
                        64, 1024, 1024, 1024, 2048, 0, b);
  grid_bar(ctr + 2, 24);
  if (b < 8) small_body(As, Bs, sentH + 65536, h1a, WxhT1, h1b,
                        64, 2048, 1024, 1024, 2048, 0, b);
  grid_bar(ctr + 3, 24);
  if (b < 8) small_body(As, Bs, h1b, hsb, WxhT2, hsb + 65536,
                        64, 2048, 1024, 1024, 2048, 0, b);
  grid_bar(ctr + 4, 24);
  if (b < 8) small_body(As, Bs, sentH + 131072, h1b, WxhT1, h1a,
                        64, 2048, 1024, 1024, 2048, 0, b);
  grid_bar(ctr + 5, 24);
  if (b < 8) small_body(As, Bs, h1a, hsb + 65536, WxhT2, hsb + 131072,
                        64, 2048, 1024, 1024, 2048, 0, b);
}

// ---------------- mid GEMM (128x128, BK=32) for ctx / cur ----------------
// MODE 0: ctx (bf16 out). MODE 1: cur -> fp8 out, value 16*tanh(...).
template <int MODE>
__global__ __launch_bounds__(256) void gemm_bf16(
    const u16* __restrict__ A, const u16* __restrict__ Bt,
    const float* __restrict__ Ww, const int* __restrict__ xtok,
    void* __restrict__ outp, int M) {
  int mt = blockIdx.x, nt = blockIdx.y, mz = blockIdx.z;
  if constexpr (MODE == 0) Bt += (long)mz << 20;  // U slice [1024][1024]

  __shared__ __align__(16) u16 As[128 * 32];
  __shared__ __align__(16) u16 Bs[128 * 32];

  const int t = threadIdx.x;
  const int w = t >> 6, l = t & 63;
  const int lr = l & 15, lg = l >> 4;
  const int wr = w >> 1, wc = w & 1;

  int ar0 = mt * 128 + (t >> 2);
  int ar1 = ar0 + 64;
  if (ar0 >= M) ar0 = 0;
  if (ar1 >= M) ar1 = 0;
  long arow0, arow1;
  if constexpr (MODE == 1) {
    arow0 = (long)(ar0 / 31) * 32 + (ar0 % 31) + 1;
    arow1 = (long)(ar1 / 31) * 32 + (ar1 % 31) + 1;
  } else {
    arow0 = ar0; arow1 = ar1;
  }

  const u16* ga0 = A + arow0 * 1024 + (t & 3) * 8;
  const u16* ga1 = A + arow1 * 1024 + (t & 3) * 8;
  const u16* gb0 = Bt + ((long)nt * 128 + (t >> 2)) * 1024 + (t & 3) * 8;
  const u16* gb1 = gb0 + 64 * 1024;

  u16* dA0 = As + w * 512; u16* dA1 = As + 2048 + w * 512;
  u16* dB0 = Bs + w * 512; u16* dB1 = Bs + 2048 + w * 512;

  f32x4 acc[4][4] = {};

  for (int kt = 0; kt < 32; ++kt) {
    __syncthreads();
    gload_lds16(ga0, dA0); gload_lds16(ga1, dA1);
    gload_lds16(gb0, dB0); gload_lds16(gb1, dB1);
    ga0 += 32; ga1 += 32; gb0 += 32; gb1 += 32;
    __syncthreads();
    bf16x8 a[4], b[4];
#pragma unroll
    for (int m = 0; m < 4; ++m)
      a[m] = *(const bf16x8*)&As[(wr * 64 + m * 16 + lr) * 32 + lg * 8];
#pragma unroll
    for (int n = 0; n < 4; ++n)
      b[n] = *(const bf16x8*)&Bs[(wc * 64 + n * 16 + lr) * 32 + lg * 8];
#pragma unroll
    for (int m = 0; m < 4; ++m)
#pragma unroll
      for (int n = 0; n < 4; ++n)
        acc[m][n] = __builtin_amdgcn_mfma_f32_16x16x32_bf16(a[m], b[n], acc[m][n], 0, 0, 0);
  }

#pragma unroll
  for (int m = 0; m < 4; ++m) {
#pragma unroll
    for (int j = 0; j < 4; ++j) {
      int r = mt * 128 + wr * 64 + m * 16 + lg * 4 + j;
      if (r >= M) continue;
      if constexpr (MODE == 0) {
        u16* oc = (u16*)outp;
#pragma unroll
        for (int n = 0; n < 4; ++n) {
          int col = nt * 128 + wc * 64 + n * 16 + lr;
          oc[((long)r * 32 + mz) * 1024 + col] = f2bf(tanhf(acc[m][n][j]));
        }
      } else {
        int sb = r / 31, l1 = r % 31;
        int s = sb >> 6, b = sb & 63;
        int widx = xtok[b * 128 + (s + 1) * 32 + l1];
        const float* wwr = Ww + (long)widx * 1024;
        u8* oc = (u8*)outp;
#pragma unroll
        for (int n = 0; n < 4; ++n) {
          int col = nt * 128 + wc * 64 + n * 16 + lr;
          oc[(long)r * 1024 + col] = f2fp8(16.f * tanhf(acc[m][n][j] + wwr[col]));
        }
      }
    }
  }
}

// ---------------- BIG GEMM: fp8, persistent 256x256, BK=64, 8-phase -----
// A,Bt are e4m3 scaled x16; epilogue scales by 1/256. LDS bytes per K-tile
// halve vs bf16 (reads 96KB+writes 32KB ~ 1500cyc < MFMA 2483) -> flips the
// dispatch from LDS-BW-bound to MFMA-bound. 1 gload per half-tile stage.
#define NOSTAGE ((void)0)
#define VM2 asm volatile("s_waitcnt vmcnt(2)" ::: "memory")
#define VM0 asm volatile("s_waitcnt vmcnt(0)" ::: "memory")

#define STAGE_A(H, KT) \
  gload_lds16(((H) ? pA1 : pA0) + (KT) * 64, \
              ldsb + ((KT) & 1) * 16384 + (H) * 8192 + w * 1024)
#define STAGE_B(H, KT) \
  gload_lds16(((H) ? pB1 : pB0) + (KT) * 64, \
              ldsb + 32768 + ((KT) & 1) * 16384 + (H) * 8192 + w * 1024)

#define PHASE(ABASE, MH, NH, RA, RB, STAGESTMT, WAITSTMT) do {             \
    if (RA) {                                                              \
      _Pragma("unroll") for (int ks = 0; ks < 2; ++ks)                     \
      _Pragma("unroll") for (int mf = 0; mf < 4; ++mf)                     \
        a[mf][ks] = *(const long*)(ldsb + (ABASE) + (MH) * 8192 + laneA +  \
                                   ks * 4096 + mf * 256);                  \
    }                                                                      \
    if (RB) {                                                              \
      _Pragma("unroll") for (int ks = 0; ks < 2; ++ks)                     \
      _Pragma("unroll") for (int nf = 0; nf < 2; ++nf)                     \
        b[NH][nf][ks] = *(const long*)(ldsb + 32768 + (ABASE) +            \
                                       (NH) * 8192 + laneB +               \
                                       ks * 4096 + nf * 256);              \
    }                                                                      \
    STAGESTMT;                                                             \
    __builtin_amdgcn_s_barrier();                                          \
    asm volatile("s_waitcnt lgkmcnt(0)" ::: "memory");                     \
    __builtin_amdgcn_sched_barrier(0);                                     \
    __builtin_amdgcn_s_setprio(1);                                         \
    _Pragma("unroll") for (int ks = 0; ks < 2; ++ks)                       \
    _Pragma("unroll") for (int mf = 0; mf < 4; ++mf)                       \
    _Pragma("unroll") for (int nf = 0; nf < 2; ++nf)                       \
      acc[(MH) * 4 + mf][(NH) * 2 + nf] =                                  \
          __builtin_amdgcn_mfma_f32_16x16x32_fp8_fp8(                      \
              a[mf][ks], b[NH][nf][ks],                                    \
              acc[(MH) * 4 + mf][(NH) * 2 + nf], 0, 0, 0);                 \
    __builtin_amdgcn_s_setprio(0);                                         \
    WAITSTMT;                                                              \
    __builtin_amdgcn_s_barrier();                                          \
  } while (0)

__global__ __launch_bounds__(512, 2) void gemm_big(
    const u8* __restrict__ A, const u8* __restrict__ Bt,
    const int* __restrict__ x, float* __restrict__ out) {
  __shared__ __align__(16) u16 lds[65536];   // staging in first 64KB; T uses all
  u8* ldsb = (u8*)lds;

  const int t = threadIdx.x;
  const int w = t >> 6, l = t & 63;
  const int lr = l & 15, lg = l >> 4;
  const int wm = w >> 2, wn = w & 3;          // 2 x 4 waves
  // fp8 frag = 8B: ds_read_b64 at [kchunk16B][row][16B] staging layout
  const int laneA = (wm * 64 + lr) * 16 + (lg >> 1) * 2048 + (lg & 1) * 8;
  const int laneB = (wn * 32 + lr) * 16 + (lg >> 1) * 2048 + (lg & 1) * 8;

  int xcd = blockIdx.x & 7, slot = blockIdx.x >> 3;   // 8 x 32

  for (int tl = slot; tl < 375; tl += 32) {
    int nt = tl / 3;                          // 0..124
    int mt = xcd * 3 + tl % 3;                // XCD owns 3 mt rows

    int arow0 = mt * 256 + (t & 127);
    int arow1 = arow0 + 128;
    int ar0c = arow0 > 5951 ? 5951 : arow0;   // pad rows: value ignored
    int ar1c = arow1 > 5951 ? 5951 : arow1;
    const u8* pA0 = A + (long)ar0c * 1024 + (t >> 7) * 16;
    const u8* pA1 = A + (long)ar1c * 1024 + (t >> 7) * 16;
    const u8* pB0 = Bt + ((long)nt * 256 + (t & 127)) * 1024 + (t >> 7) * 16;
    const u8* pB1 = pB0 + 128 * 1024;

    f32x4 acc[8][4] = {};
    long a[4][2], b[2][2][2];

    // prologue: 6 half-tile stages (1 gload each); VM2 retires tile 0
    STAGE_A(0, 0); STAGE_B(0, 0); STAGE_B(1, 0); STAGE_A(1, 0);
    STAGE_A(0, 1); STAGE_B(0, 1);
    VM2;
    __builtin_amdgcn_s_barrier();

    for (int g = 0; g < 14; g += 2) {
      PHASE(0,     0, 0, 1, 1, STAGE_B(1, g + 1), NOSTAGE);
      PHASE(0,     0, 1, 0, 1, STAGE_A(1, g + 1), NOSTAGE);
      PHASE(0,     1, 0, 1, 0, STAGE_A(0, g + 2), NOSTAGE);
      PHASE(0,     1, 1, 0, 0, STAGE_B(0, g + 2), VM2);
      PHASE(16384, 0, 0, 1, 1, STAGE_B(1, g + 2), NOSTAGE);
      PHASE(16384, 0, 1, 0, 1, STAGE_A(1, g + 2), NOSTAGE);
      PHASE(16384, 1, 0, 1, 0, STAGE_A(0, g + 3), NOSTAGE);
      PHASE(16384, 1, 1, 0, 0, STAGE_B(0, g + 3), VM2);
    }
    // group 14 (buf 0): stage tile 15's trailing halves
    PHASE(0,     0, 0, 1, 1, STAGE_B(1, 15), NOSTAGE);
    PHASE(0,     0, 1, 0, 1, STAGE_A(1, 15), NOSTAGE);
    PHASE(0,     1, 0, 1, 0, NOSTAGE, NOSTAGE);
    PHASE(0,     1, 1, 0, 0, NOSTAGE, VM0);
    // group 15 (buf 1): pure drain
    PHASE(16384, 0, 0, 1, 1, NOSTAGE, NOSTAGE);
    PHASE(16384, 0, 1, 0, 1, NOSTAGE, NOSTAGE);
    PHASE(16384, 1, 0, 1, 0, NOSTAGE, NOSTAGE);
    PHASE(16384, 1, 1, 0, 0, NOSTAGE, NOSTAGE);

    // epilogue: per-wave LDS transpose -> 128B-line NT dwordx4; stores not
    // drained here (next prologue's VM2 subsumes them, in-order retirement).
    float* T = (float*)lds + w * 2112;
#pragma unroll
    for (int mh = 0; mh < 2; ++mh)
#pragma unroll
      for (int nh = 0; nh < 2; ++nh) {
#pragma unroll
        for (int mf = 0; mf < 4; ++mf)
#pragma unroll
          for (int j = 0; j < 4; ++j)
#pragma unroll
            for (int nf = 0; nf < 2; ++nf)
              T[(mf * 16 + lg * 4 + j) * 33 + nf * 16 + lr] =
                  acc[mh * 4 + mf][nh * 2 + nf][j] * (1.f / 256.f);
#pragma unroll
        for (int i = 0; i < 8; ++i) {
          int row = (l >> 3) + 8 * i;
          int c4 = (l & 7) * 4;
          f32x4 v;
          v[0] = T[row * 33 + c4];     v[1] = T[row * 33 + c4 + 1];
          v[2] = T[row * 33 + c4 + 2]; v[3] = T[row * 33 + c4 + 3];
          int r = mt * 256 + mh * 128 + wm * 64 + row;
          int colb = nt * 256 + nh * 128 + wn * 32 + c4;
          float* o;
          if (r < 5952) {
            int s = r / 1984, rem = r % 1984;
            int bb = rem / 31, l1 = rem % 31;
            o = out + ((long)bb * 96 + s * 32 + l1 + 1) * 32000 + colb;
          } else {
            int i2 = r - 5952;
            int s = i2 >> 6, bb = i2 & 63;
            int tok = x[bb * 128 + (s + 1) * 32];
            v[0] = (colb == tok);     v[1] = (colb + 1 == tok);
            v[2] = (colb + 2 == tok); v[3] = (colb + 3 == tok);
            o = out + ((long)bb * 96 + s * 32) * 32000 + colb;
          }
          __builtin_nontemporal_store(v, (f32x4*)o);
        }
      }
    __builtin_amdgcn_s_barrier();
  }
}

// ------------------------------- launch ---------------------------------
extern "C" void kernel_launch(void* const* d_in, const int* in_sizes, int n_in,
                              void* d_out, int out_size, void* d_ws, size_t ws_size,
                              hipStream_t stream) {
  const int*   x    = (const int*)d_in[0];
  const float* emb  = (const float*)d_in[2];
  const float* Wcsm = (const float*)d_in[3];
  const float* Wx1  = (const float*)d_in[4];
  const float* Wh1  = (const float*)d_in[5];
  const float* Wx2  = (const float*)d_in[6];
  const float* Wh2  = (const float*)d_in[7];
  const float* U    = (const float*)d_in[8];
  const float* Ww   = (const float*)d_in[9];
  const float* Wc   = (const float*)d_in[10];
  const float* Wfc  = (const float*)d_in[11];
  float* out = (float*)d_out;

  char* ws = (char*)d_ws;
  u16* sentM = (u16*)(ws + 0);          //  196608 [192][512]
  u16* sentH = (u16*)(ws + 196608);     //  393216 [192][1024]
  u16* h1a   = (u16*)(ws + 589824);     //  131072 [64][1024]
  u16* h1b   = (u16*)(ws + 720896);     //  131072
  u16* hsb   = (u16*)(ws + 851968);     //  393216 [192][1024]
  u16* ctx   = (u16*)(ws + 1245184);    // 12582912 [192*32][1024] bf16
  u16* WcsmT = (u16*)(ws + 1245184);    //  1048576 (pre-ctx)
  u16* WxhT1 = (u16*)(ws + 2293760);    //  4194304 (pre-ctx)
  u16* WxhT2 = (u16*)(ws + 6488064);    //  4194304 (pre-ctx)
  u8*  curf  = (u8*)(ws + 13828096);    //  6094848 [5952][1024] fp8 (x16)
  u16* WcT   = (u16*)(ws + 26017792);   //  2097152 [1024][1024] bf16
  u16* BIG   = (u16*)(ws + 28114944);   // 67108864 U^T bf16, then Wfc^T fp8
  int* ctr   = (int*)(ws + 28114944 + 67108864 - 64);

  TJobs jobs;
  jobs.j[0] = {Wx1,  WxhT1,        1024, 2048};
  jobs.j[1] = {Wh1,  WxhT1 + 1024, 1024, 2048};
  jobs.j[2] = {Wx2,  WxhT2,        1024, 2048};
  jobs.j[3] = {Wh2,  WxhT2 + 1024, 1024, 2048};
  jobs.j[4] = {Wc,   WcT,          1024, 1024};
  jobs.j[5] = {Wcsm, WcsmT,         512,  512};
  transpose64_multi<<<dim3(32, 16, 6), 256, 0, stream>>>(jobs);

  meanpool_k<<<192, 256, 0, stream>>>(x, emb, sentM);
  hipMemsetAsync((void*)ctr, 0, 64, stream);
  rnn_chain<<<24, 256, 0, stream>>>(sentM, sentH, h1a, h1b, hsb,
                                    WcsmT, WxhT1, WxhT2, ctr);

  // contexts: per-m GEMM against U[m]^T (bf16)
  transpose64<<<dim3(32, 16, 32), 256, 0, stream>>>(U, BIG, 1024, 1024, 1024);
  gemm_bf16<0><<<dim3(2, 8, 32), 256, 0, stream>>>(hsb, BIG, nullptr, nullptr, (void*)ctx, 192);

  // cur: GEMM against Wc^T; epilogue writes fp8 (value x16)
  gemm_bf16<1><<<dim3(47, 8, 1), 256, 0, stream>>>(ctx, WcT, Ww, x, (void*)curf, 5952);

  // y_sec: fp8 persistent 8-phase 256^2 GEMM vs Wfc^T(fp8); writes all d_out
  transpose64_f8<<<dim3(1000, 16, 1), 256, 0, stream>>>(Wfc, (u8*)BIG, 32000, 1024);
  gemm_big<<<256, 512, 0, stream>>>(curf, (u8*)BIG, x, out);
}